// Round 2
// baseline (879.053 us; speedup 1.0000x reference)
//
#include <hip/hip_runtime.h>
#include <cstdint>
#include <cstddef>

// Problem constants (reference: B=2,S=1024,HID=4096,H=32,D=128,KVH=8,EH=8,AH=256)
#define B_    2
#define S_    1024
#define HID_  4096
#define H_    32
#define D_    128
#define KVH_  8
#define EH_   8
#define AH_   256
#define NTOK  2048

typedef unsigned short u16;
typedef __attribute__((ext_vector_type(8))) short bf16x8;
typedef __attribute__((ext_vector_type(4))) float f32x4;
typedef const __attribute__((address_space(1))) void* gp_t;
typedef __attribute__((address_space(3))) void* lp_t;

__device__ __forceinline__ u16 f2bf(float f) {              // RNE f32->bf16
  unsigned u = __float_as_uint(f);
  return (u16)((u + 0x7FFF + ((u >> 16) & 1)) >> 16);
}
__device__ __forceinline__ float bf2f(u16 u) {
  return __uint_as_float((unsigned)u << 16);
}

// --------------- token-type scan: inv[] + counts (1 block) ---------------
// inv[t] = compact index within its type. cnt = {ntext, ntext_pad, nent,
// nent_pad, ceil128(nent*8), _}
__global__ __launch_bounds__(1024) void build_inv(
    const int* __restrict__ ttm, int* __restrict__ inv, int* __restrict__ cnt)
{
  __shared__ int a[NTOK], b[NTOK];
  const int t = threadIdx.x;
  for (int i = t; i < NTOK; i += 1024) a[i] = (ttm[i] != 1) ? 1 : 0;
  __syncthreads();
  int* src = a; int* dst = b;
  for (int off = 1; off < NTOK; off <<= 1) {
    for (int i = t; i < NTOK; i += 1024)
      dst[i] = src[i] + ((i >= off) ? src[i - off] : 0);
    __syncthreads();
    int* tmp = src; src = dst; dst = tmp;
  }
  for (int i = t; i < NTOK; i += 1024) {
    const int txt = (ttm[i] != 1);
    const int excl = src[i] - txt;
    inv[i] = txt ? excl : (i - excl);
  }
  if (t == 0) {
    const int ntext = src[NTOK - 1];
    const int nent = NTOK - ntext;
    cnt[0] = ntext;
    cnt[1] = (ntext + 127) & ~127;
    cnt[2] = nent;
    cnt[3] = (nent + 127) & ~127;
    cnt[4] = (nent * 8 + 127) & ~127;
  }
}

// --------------- gather inputs to per-type compact bf16 ---------------
__global__ __launch_bounds__(256) void gather_cast(
    const float* __restrict__ x_text, const float* __restrict__ x_ent,
    const int* __restrict__ ttm, const int* __restrict__ inv,
    u16* __restrict__ xt, u16* __restrict__ xe)
{
  const int tok = blockIdx.x;
  const int j = inv[tok];
  const int t = threadIdx.x;
  if (ttm[tok] != 1) {
    const float* src = x_text + (size_t)tok * HID_;
    u16* dst = xt + (size_t)j * HID_;
#pragma unroll
    for (int i = 0; i < 4; i++) {
      const int c = (i * 256 + t) * 4;
      const float4 v = *(const float4*)(src + c);
      ushort4 o; o.x = f2bf(v.x); o.y = f2bf(v.y); o.z = f2bf(v.z); o.w = f2bf(v.w);
      *(ushort4*)(dst + c) = o;
    }
  } else {
    const float* src = x_ent + (size_t)tok * 1024;
    u16* dst = xe + (size_t)j * 1024;
    const int c = t * 4;
    const float4 v = *(const float4*)(src + c);
    ushort4 o; o.x = f2bf(v.x); o.y = f2bf(v.y); o.z = f2bf(v.z); o.w = f2bf(v.w);
    *(ushort4*)(dst + c) = o;
  }
}

// ---------------- batched weight transpose+cast ----------------
struct TSeg { const float* W; u16* Wt; int K; int N; int blk0; };
struct TArgs { TSeg s[12]; int nseg; };

__global__ __launch_bounds__(256) void batch_transpose(TArgs args)
{
  int seg = 0;
#pragma unroll
  for (int i = 1; i < 12; i++)
    if (i < args.nseg && (int)blockIdx.x >= args.s[i].blk0) seg = i;
  const float* W = args.s[seg].W;
  u16* Wt = args.s[seg].Wt;
  const int K = args.s[seg].K, N = args.s[seg].N;
  const int local = blockIdx.x - args.s[seg].blk0;

  __shared__ float tle[32][33];
  const int tid = threadIdx.x;
  const int tx = tid & 31, ty = tid >> 5;
  const int nb = N >> 5;
  const int k0 = (local / nb) << 5;
  const int n0 = (local % nb) << 5;
#pragma unroll
  for (int r = 0; r < 32; r += 8)
    tle[ty + r][tx] = W[(size_t)(k0 + ty + r) * N + n0 + tx];
  __syncthreads();
#pragma unroll
  for (int r = 0; r < 32; r += 8)
    Wt[(size_t)(n0 + ty + r) * K + k0 + tx] = f2bf(tle[tx][ty + r]);
}

// --------------------- bf16 MFMA GEMM (128x128 tile, 4-deep pipelined) ---------------------
// C[M,N] bf16 = act(A @ Bt^T + bias). Early-exit rows >= *mlim.
// astride!=0: A row addressing = (row>>3)*astride + (row&7)*K
//
// Block-index mapping: m204 bijective XCD swizzle + COLUMN-major tile order.
// Each XCD owns a contiguous strip of N-column tiles, so each B-panel (the
// large operand, e.g. 50 MB for QKV) is fetched into exactly one XCD-L2 once
// instead of streaming across all 8 L2s -> cuts cross-fabric read traffic
// ~5x on the big GEMMs (measured regime: 768 MB logical reads / 134 us =
// 5.7 TB/s = fabric-BW-bound). Within a column, rows are taken stride-nTM/8
// so mlim early-exit rows stay balanced across XCDs.
__global__ __launch_bounds__(256) void gemm_bt_bf16(
    const u16* __restrict__ A, const u16* __restrict__ Bt,
    const float* __restrict__ bias, u16* __restrict__ C,
    int M, int N, int K, int act, int astride, const int* __restrict__ mlim)
{
  const int nTN = N >> 7;
  const int nTM = (int)gridDim.x / nTN;
  const int nwg = nTM * nTN;
  const int bid = (int)blockIdx.x;
  const int xcd = bid & 7, lix = bid >> 3;
  const int q = nwg >> 3, rr_ = nwg & 7;
  const int wgid = (xcd < rr_ ? xcd * (q + 1) : rr_ * (q + 1) + (xcd - rr_) * q) + lix;
  const int tcol = wgid / nTM;
  int trow = wgid - tcol * nTM;
  if ((nTM & 7) == 0) trow = ((trow & 7) * (nTM >> 3)) + (trow >> 3);
  const int m0 = trow << 7;
  if (mlim && m0 >= *mlim) return;
  const int n0 = tcol << 7;

  __shared__ __align__(16) char AsB[4][8192];
  __shared__ __align__(16) char BsB[4][8192];

  const int tid = threadIdx.x;
  const int wave = tid >> 6, lane = tid & 63;
  const int wm = ((wave >> 1) << 6);
  const int wn = ((wave & 1) << 6);
  const int l16 = lane & 15, lg = lane >> 4;

  const int ofs0 = (wave * 2) * 1024;
  const int flat0 = ofs0 + lane * 16;
  const int flat1 = flat0 + 1024;
  const int g0 = flat0 >> 11, r0 = (flat0 & 2047) >> 4;
  const int g1 = flat1 >> 11, r1 = (flat1 & 2047) >> 4;

  auto arow = [&](int row) -> size_t {
    return astride ? (size_t)(row >> 3) * astride + (size_t)(row & 7) * K
                   : (size_t)row * K;
  };
  const u16* a0 = A + arow(m0 + r0) + g0 * 8;
  const u16* a1 = A + arow(m0 + r1) + g1 * 8;
  const u16* b0 = Bt + (size_t)(n0 + r0) * K + g0 * 8;
  const u16* b1 = Bt + (size_t)(n0 + r1) * K + g1 * 8;

  f32x4 acc[4][4];
#pragma unroll
  for (int i = 0; i < 4; i++)
#pragma unroll
    for (int j = 0; j < 4; j++) acc[i][j] = (f32x4)0.f;

  const int nk = K >> 5;  // number of 32-wide K-tiles; nk >= 4 required

  auto stage = [&](int buf) {
    __builtin_amdgcn_global_load_lds((gp_t)a0, (lp_t)(&AsB[buf][ofs0]),        16, 0, 0);
    __builtin_amdgcn_global_load_lds((gp_t)a1, (lp_t)(&AsB[buf][ofs0 + 1024]), 16, 0, 0);
    __builtin_amdgcn_global_load_lds((gp_t)b0, (lp_t)(&BsB[buf][ofs0]),        16, 0, 0);
    __builtin_amdgcn_global_load_lds((gp_t)b1, (lp_t)(&BsB[buf][ofs0 + 1024]), 16, 0, 0);
    a0 += 32; a1 += 32; b0 += 32; b1 += 32;
  };

  auto compute = [&](int buf) {
    bf16x8 af[4], bv[4];
#pragma unroll
    for (int i = 0; i < 4; i++)
      af[i] = *(const bf16x8*)(&AsB[buf][lg * 2048 + (wm + 16 * i + l16) * 16]);
#pragma unroll
    for (int j = 0; j < 4; j++)
      bv[j] = *(const bf16x8*)(&BsB[buf][lg * 2048 + (wn + 16 * j + l16) * 16]);
#pragma unroll
    for (int i = 0; i < 4; i++)
#pragma unroll
      for (int j = 0; j < 4; j++)
        acc[i][j] = __builtin_amdgcn_mfma_f32_16x16x32_bf16(af[i], bv[j], acc[i][j], 0, 0, 0);
  };

  // prologue: fill the 4-deep pipe (16 loads/wave outstanding)
#pragma unroll
  for (int t = 0; t < 4; t++) stage(t);

  int k = 0;
  // steady state: wait only for the oldest K-tile (12 loads = 3 tiles in flight)
  for (; k + 4 < nk; ++k) {
    asm volatile("s_waitcnt vmcnt(12)");
    __builtin_amdgcn_s_barrier();
    asm volatile("" ::: "memory");
    compute(k & 3);
    asm volatile("" ::: "memory");
    __builtin_amdgcn_s_barrier();
    stage(k & 3);
  }
  // drain: 4 remaining buffers, vmcnt 12 -> 8 -> 4 -> 0
  asm volatile("s_waitcnt vmcnt(12)");
  __builtin_amdgcn_s_barrier();
  asm volatile("" ::: "memory");
  compute(k & 3); ++k;
  asm volatile("s_waitcnt vmcnt(8)");
  __builtin_amdgcn_s_barrier();
  asm volatile("" ::: "memory");
  compute(k & 3); ++k;
  asm volatile("s_waitcnt vmcnt(4)");
  __builtin_amdgcn_s_barrier();
  asm volatile("" ::: "memory");
  compute(k & 3); ++k;
  asm volatile("s_waitcnt vmcnt(0)");
  __builtin_amdgcn_s_barrier();
  asm volatile("" ::: "memory");
  compute(k & 3);

  // epilogue: C/D map col=lane&15, row=(lane>>4)*4+reg
#pragma unroll
  for (int i = 0; i < 4; i++) {
#pragma unroll
    for (int r = 0; r < 4; r++) {
      const int row = m0 + wm + 16 * i + lg * 4 + r;
#pragma unroll
      for (int j = 0; j < 4; j++) {
        const int col = n0 + wn + 16 * j + l16;
        float c = acc[i][j][r];
        if (bias) c += bias[col];
        if (act) c = 0.5f * c * (1.f + erff(c * 0.70710678118654752f));  // exact GELU
        C[(size_t)row * N + col] = f2bf(c);
      }
    }
  }
}

// ------------- select + RoPE -> bf16 Q (prescaled), bf16 K (full token index) -------------
// text: qkv compact bf16 [ntext][6144] (q @ h*128, k @ 4096+hk*128)
// entity: qe/ke compact bf16 [nent*8][128]
__global__ __launch_bounds__(256) void select_rope_bf(
    const u16* __restrict__ qkv, const u16* __restrict__ qe,
    const u16* __restrict__ ke, u16* __restrict__ Qb, u16* __restrict__ Kb,
    const int* __restrict__ ttm, const int* __restrict__ inv,
    const int* __restrict__ pid)
{
  __shared__ float cs[64], sn[64];
  const int token = blockIdx.x;
  const bool is_e = (ttm[token] == 1);
  const int j = inv[token];
  const int t = threadIdx.x;
  if (t < 64) {
    const float pos = (float)pid[token];
    const float iv = __expf(-((float)(2 * t) * (1.f / 128.f)) * 9.210340371976184f);
    const float f = pos * iv;
    cs[t] = cosf(f); sn[t] = sinf(f);
  }
  __syncthreads();
  const float scale = 0.08838834764831845f;  // 1/sqrt(128) folded into Q
  const u16* qrow = qkv + (size_t)j * 6144;

  for (int it = t; it < H_ * 64; it += 256) {
    const int h = it >> 6, i = it & 63;
    float x1, x2;
    if (is_e) {
      const size_t eb = ((size_t)j * 8 + (h & 7)) * D_;
      x1 = bf2f(qe[eb + i]); x2 = bf2f(qe[eb + i + 64]);
    } else {
      x1 = bf2f(qrow[h * 128 + i]); x2 = bf2f(qrow[h * 128 + i + 64]);
    }
    const size_t base = ((size_t)token * H_ + h) * D_;
    Qb[base + i]      = f2bf((x1 * cs[i] - x2 * sn[i]) * scale);
    Qb[base + i + 64] = f2bf((x2 * cs[i] + x1 * sn[i]) * scale);
  }
  for (int it = t; it < KVH_ * 64; it += 256) {
    const int h = it >> 6, i = it & 63;
    float x1, x2;
    if (is_e) {
      const size_t eb = ((size_t)j * 8 + h) * D_;
      x1 = bf2f(ke[eb + i]); x2 = bf2f(ke[eb + i + 64]);
    } else {
      x1 = bf2f(qrow[4096 + h * 128 + i]); x2 = bf2f(qrow[4096 + h * 128 + i + 64]);
    }
    const size_t base = ((size_t)token * KVH_ + h) * D_;
    Kb[base + i]      = f2bf(x1 * cs[i] - x2 * sn[i]);
    Kb[base + i + 64] = f2bf(x2 * cs[i] + x1 * sn[i]);
  }
}

// ---------- V select + transpose: VT[b][hk][d][s] bf16 ----------
__global__ __launch_bounds__(256) void vtrans_kernel(
    const u16* __restrict__ qkv, const u16* __restrict__ ve,
    const int* __restrict__ ttm, const int* __restrict__ inv,
    u16* __restrict__ VTg)
{
  __shared__ float t[32][33];
  const int dt = blockIdx.x & 3;
  const int st = (blockIdx.x >> 2) & 31;
  const int hk = (blockIdx.x >> 7) & 7;
  const int b  = blockIdx.x >> 10;
  const int s0 = st * 32, d0 = dt * 32;
  const int tx = threadIdx.x & 31, ty = threadIdx.x >> 5;
#pragma unroll
  for (int i = 0; i < 4; i++) {
    const int r = ty + 8 * i;
    const int tok = b * S_ + s0 + r;
    const int j = inv[tok];
    t[r][tx] = (ttm[tok] == 1)
        ? bf2f(ve[((size_t)j * 8 + hk) * D_ + d0 + tx])
        : bf2f(qkv[(size_t)j * 6144 + 5120 + hk * 128 + d0 + tx]);
  }
  __syncthreads();
#pragma unroll
  for (int i = 0; i < 4; i++) {
    const int rr = ty + 8 * i;
    VTg[((size_t)(b * KVH_ + hk) * D_ + d0 + rr) * S_ + s0 + tx] = f2bf(t[tx][rr]);
  }
}

// ------------------- MFMA causal GQA flash attention (compact output) -------------------
__global__ __launch_bounds__(256) void attn_mfma(
    const u16* __restrict__ Qb, const u16* __restrict__ Kb,
    const u16* __restrict__ VTg, u16* __restrict__ O,
    const int* __restrict__ ttm, const int* __restrict__ inv,
    const int* __restrict__ cnt)
{
  __shared__ __align__(16) u16 Ks[16 * 64 * 8];
  __shared__ __align__(16) u16 VTs[8 * 128 * 8];
  __shared__ __align__(16) float Ps[4][16 * 68];

  const int tid = threadIdx.x;
  const int wave = tid >> 6, lane = tid & 63;
  const int l16 = lane & 15, lg = lane >> 4;

  const int qtile = 15 - (blockIdx.x & 15);
  const int h = (blockIdx.x >> 4) & (H_ - 1);
  const int b = blockIdx.x >> 9;
  const int q0 = qtile * 64;
  const int hk = h & 7;
  const int qw = q0 + 16 * wave;
  const int qmax = qw + 15;

  bf16x8 qf[4];
  {
    const u16* qrow = Qb + ((size_t)(b * S_ + qw + l16) * H_ + h) * D_;
#pragma unroll
    for (int c = 0; c < 4; c++)
      qf[c] = *(const bf16x8*)(qrow + c * 32 + lg * 8);
  }

  f32x4 o[8];
#pragma unroll
  for (int nt = 0; nt < 8; nt++) o[nt] = (f32x4)0.f;
  float mrun[4] = {-1e30f, -1e30f, -1e30f, -1e30f};
  float lrun[4] = {0.f, 0.f, 0.f, 0.f};

  const int ntiles = qtile + 1;
  for (int t = 0; t < ntiles; t++) {
    const int k0 = t * 64;
    if (t) __syncthreads();
#pragma unroll
    for (int i = 0; i < 4; i++) {
      const int idx = i * 256 + tid;
      const int g = idx >> 6, key = idx & 63;
      *(bf16x8*)(Ks + idx * 8) =
          *(const bf16x8*)(Kb + ((size_t)(b * S_ + k0 + key) * KVH_ + hk) * D_ + g * 8);
    }
#pragma unroll
    for (int i = 0; i < 4; i++) {
      const int idx = i * 256 + tid;
      const int kg = idx >> 7, d = idx & 127;
      *(bf16x8*)(VTs + idx * 8) =
          *(const bf16x8*)(VTg + ((size_t)(b * KVH_ + hk) * D_ + d) * S_ + k0 + kg * 8);
    }
    __syncthreads();

    if (k0 > qmax) continue;

    f32x4 s[4];
#pragma unroll
    for (int c = 0; c < 4; c++) s[c] = (f32x4)0.f;
#pragma unroll
    for (int c = 0; c < 4; c++)
#pragma unroll
      for (int dc = 0; dc < 4; dc++) {
        const bf16x8 kf = *(const bf16x8*)(Ks + ((dc * 4 + lg) * 64 + c * 16 + l16) * 8);
        s[c] = __builtin_amdgcn_mfma_f32_16x16x32_bf16(qf[dc], kf, s[c], 0, 0, 0);
      }

    float p[4][4], alpha[4];
#pragma unroll
    for (int r = 0; r < 4; r++) {
      const int qg = qw + lg * 4 + r;
      float sv[4], mx = -1e30f;
#pragma unroll
      for (int c = 0; c < 4; c++) {
        const int kg_ = k0 + c * 16 + l16;
        float v = (kg_ <= qg) ? s[c][r] : -1e30f;
        sv[c] = v;
        mx = fmaxf(mx, v);
      }
#pragma unroll
      for (int off = 1; off < 16; off <<= 1)
        mx = fmaxf(mx, __shfl_xor(mx, off));
      const float mn = fmaxf(mrun[r], mx);
      alpha[r] = __expf(mrun[r] - mn);
      mrun[r] = mn;
      float rs = 0.f;
#pragma unroll
      for (int c = 0; c < 4; c++) { p[c][r] = __expf(sv[c] - mn); rs += p[c][r]; }
#pragma unroll
      for (int off = 1; off < 16; off <<= 1)
        rs += __shfl_xor(rs, off);
      lrun[r] = lrun[r] * alpha[r] + rs;
    }
#pragma unroll
    for (int nt = 0; nt < 8; nt++)
#pragma unroll
      for (int r = 0; r < 4; r++) o[nt][r] *= alpha[r];

    float* pw = Ps[wave];
#pragma unroll
    for (int c = 0; c < 4; c++)
#pragma unroll
      for (int r = 0; r < 4; r++)
        pw[(lg * 4 + r) * 68 + c * 16 + l16] = p[c][r];

    bf16x8 pa[2];
#pragma unroll
    for (int kc = 0; kc < 2; kc++) {
      const float* src = pw + l16 * 68 + kc * 32 + lg * 8;
      const float4 f0 = *(const float4*)(src);
      const float4 f1 = *(const float4*)(src + 4);
      bf16x8 v;
      v[0] = (short)f2bf(f0.x); v[1] = (short)f2bf(f0.y);
      v[2] = (short)f2bf(f0.z); v[3] = (short)f2bf(f0.w);
      v[4] = (short)f2bf(f1.x); v[5] = (short)f2bf(f1.y);
      v[6] = (short)f2bf(f1.z); v[7] = (short)f2bf(f1.w);
      pa[kc] = v;
    }

#pragma unroll
    for (int nt = 0; nt < 8; nt++)
#pragma unroll
      for (int kc = 0; kc < 2; kc++) {
        const bf16x8 vf = *(const bf16x8*)(VTs + ((kc * 4 + lg) * 128 + nt * 16 + l16) * 8);
        o[nt] = __builtin_amdgcn_mfma_f32_16x16x32_bf16(pa[kc], vf, o[nt], 0, 0, 0);
      }
  }

  // epilogue -> compact row: text j, entity ntext_pad + j
  const int ntext_pad = cnt[1];
#pragma unroll
  for (int r = 0; r < 4; r++) {
    const float inv_l = 1.f / lrun[r];
    const int tok = b * S_ + qw + lg * 4 + r;
    const int j = inv[tok];
    const int crow = (ttm[tok] != 1) ? j : (ntext_pad + j);
    u16* orow = O + (size_t)crow * (H_ * D_) + h * D_ + l16;
#pragma unroll
    for (int nt = 0; nt < 8; nt++)
      orow[nt * 16] = f2bf(o[nt][r] * inv_l);
  }
}

// ------------------- mean over 4 head-replicas (entity-compact) -------------------
__global__ __launch_bounds__(256) void mean_heads_kernel(
    const u16* __restrict__ attn, u16* __restrict__ oe, const int* __restrict__ cnt)
{
  const size_t idx = (size_t)blockIdx.x * 256 + threadIdx.x;
  const int j = (int)(idx >> 10);
  if (j >= cnt[2]) return;
  const int r = (int)(idx & 1023);
  const int h = r >> 7, d = r & 127;
  const u16* a = attn + (size_t)(cnt[1] + j) * (H_ * D_);
  const float s = 0.25f * (bf2f(a[h * D_ + d]) + bf2f(a[(8 + h) * D_ + d]) +
                           bf2f(a[(16 + h) * D_ + d]) + bf2f(a[(24 + h) * D_ + d]));
  oe[idx] = f2bf(s);
}

// ------------------- scatter compact outs -> d_out with type masking -------------------
__global__ __launch_bounds__(256) void scatter_out(
    const u16* __restrict__ ct, const u16* __restrict__ ce,
    const int* __restrict__ ttm, const int* __restrict__ inv,
    float* __restrict__ out_text, float* __restrict__ out_ent)
{
  const int tok = blockIdx.x;
  const bool is_e = (ttm[tok] == 1);
  const int j = inv[tok];
  const int t = threadIdx.x;
  float* ot = out_text + (size_t)tok * HID_;
#pragma unroll
  for (int i = 0; i < 4; i++) {
    const int c = (i * 256 + t) * 4;
    float4 v = make_float4(0.f, 0.f, 0.f, 0.f);
    if (!is_e) {
      const ushort4 u = *(const ushort4*)(ct + (size_t)j * HID_ + c);
      v.x = bf2f(u.x); v.y = bf2f(u.y); v.z = bf2f(u.z); v.w = bf2f(u.w);
    }
    *(float4*)(ot + c) = v;
  }
  float* oe_ = out_ent + (size_t)tok * 1024;
  {
    const int c = t * 4;
    float4 v = make_float4(0.f, 0.f, 0.f, 0.f);
    if (is_e) {
      const ushort4 u = *(const ushort4*)(ce + (size_t)j * 1024 + c);
      v.x = bf2f(u.x); v.y = bf2f(u.y); v.z = bf2f(u.z); v.w = bf2f(u.w);
    }
    *(float4*)(oe_ + c) = v;
  }
}

// ------------------------------- launcher -------------------------------
extern "C" void kernel_launch(void* const* d_in, const int* in_sizes, int n_in,
                              void* d_out, int out_size, void* d_ws, size_t ws_size,
                              hipStream_t stream)
{
  const float* x_text = (const float*)d_in[0];
  const float* x_ent  = (const float*)d_in[1];
  const float* wq_t   = (const float*)d_in[2];
  const float* wk_t   = (const float*)d_in[3];
  const float* wv_t   = (const float*)d_in[4];
  const float* wo_t   = (const float*)d_in[5];
  const float* wq_e   = (const float*)d_in[6];
  const float* wk_e   = (const float*)d_in[7];
  const float* wv_e   = (const float*)d_in[8];
  const float* wo_e   = (const float*)d_in[9];
  const float* aq1_w = (const float*)d_in[10]; const float* aq1_b = (const float*)d_in[11];
  const float* aq2_w = (const float*)d_in[12]; const float* aq2_b = (const float*)d_in[13];
  const float* ak1_w = (const float*)d_in[14]; const float* ak1_b = (const float*)d_in[15];
  const float* ak2_w = (const float*)d_in[16]; const float* ak2_b = (const float*)d_in[17];
  const float* av1_w = (const float*)d_in[18]; const float* av1_b = (const float*)d_in[19];
  const float* av2_w = (const float*)d_in[20]; const float* av2_b = (const float*)d_in[21];
  const float* ao1_w = (const float*)d_in[22]; const float* ao1_b = (const float*)d_in[23];
  const float* ao2_w = (const float*)d_in[24]; const float* ao2_b = (const float*)d_in[25];
  const int*   ttm   = (const int*)d_in[27];
  const int*   pid   = (const int*)d_in[28];

  float* out_text = (float*)d_out;                       // [2048,4096]
  float* out_ent  = out_text + (size_t)B_ * S_ * HID_;   // [2048,1024]

  // ---- workspace layout (bytes), peak ~132.5 MB (proven cap >= 142.6) ----
  char* w = (char*)d_ws;
  // R0 phase 1-2:
  u16*   qkv_bf = (u16*)(w + 0);             // 25,165,824  [2048][6144] compact text
  u16*   qe     = (u16*)(w + 25165824);      //  4,194,304  [2048*8][128] compact ent
  u16*   ke     = (u16*)(w + 29360128);      //  4,194,304
  u16*   ve     = (u16*)(w + 33554432);      //  4,194,304
  u16*   h1     = (u16*)(w + 37748736);      //  8,388,608  [16384][256]
  // R0 phase 3-4 overlays:
  u16*   attn_bf = (u16*)(w + 0);            // 17,825,792  [2176][4096] compact
  u16*   oe_bf   = (u16*)(w + 17825792);     //  4,194,304
  u16*   h1o     = (u16*)(w + 22020096);     //  8,388,608
  u16*   oe2     = (u16*)(w + 30408704);     //  4,194,304
  // R1: xt_bf -> e_all -> Q_bf -> ct_out
  u16*   xt_bf = (u16*)(w + 50331648);       // 16,777,216  [2048][4096] compact text
  u16*   e_all = (u16*)(w + 50331648);       // 12,582,912  [2048][3072] compact ent
  u16*   Q_bf  = (u16*)(w + 50331648);       // 16,777,216  full-token
  u16*   ct_out = (u16*)(w + 50331648);      // 16,777,216  wo_t compact C
  // R2: xe_bf -> K_bf -> ce_out
  u16*   xe_bf = (u16*)(w + 67108864);       //  4,194,304  [2048][1024] compact ent
  u16*   K_bf  = (u16*)(w + 67108864);       //  4,194,304  full-token
  u16*   ce_out = (u16*)(w + 67108864);      //  4,194,304  wo_e compact C
  // R3: WTb -> (phase 2+) WTo/WTao/WToe
  u16*   WTb   = (u16*)(w + 71303168);       // 50,331,648  [6144][4096]
  u16*   WTo   = (u16*)(w + 71303168);       // 33,554,432  [4096][4096]
  u16*   WTao1 = (u16*)(w + 104857600);      //     65,536
  u16*   WTao2 = (u16*)(w + 104923136);      //     65,536
  u16*   WToe  = (u16*)(w + 104988672);      //  2,097,152
  // R4/R5: entity weights
  u16*   WTe   = (u16*)(w + 121634816);      //  6,291,456  [3072][1024]
  u16*   WTa   = (u16*)(w + 127926272);      //    393,216  6 x [.][.]
  // R6/R7:
  u16*   VT_g  = (u16*)(w + 128319488);      //  4,194,304
  int*   inv   = (int*)(w + 132513792);      //      8,192
  int*   cnt   = (int*)(w + 132521984);      //         64

  auto G = [&](const u16* A, const u16* Bt, const float* bias, u16* C,
               int M, int N, int K, int act, int astride, const int* mlim) {
    gemm_bt_bf16<<<dim3((M >> 7) * (N >> 7)), dim3(256), 0, stream>>>(
        A, Bt, bias, C, M, N, K, act, astride, mlim);
  };

  // weight transposes, batch 1 (everything pre-attention)
  {
    TArgs ta{}; int blk = 0, s = 0;
    auto add = [&](const float* W, u16* Wt, int K, int N) {
      ta.s[s] = {W, Wt, K, N, blk}; blk += (K >> 5) * (N >> 5); s++;
    };
    add(wq_t, WTb, HID_, HID_);
    add(wk_t, WTb + (size_t)4096 * HID_, HID_, 1024);
    add(wv_t, WTb + (size_t)5120 * HID_, HID_, 1024);
    add(wq_e, WTe, 1024, 1024);
    add(wk_e, WTe + (size_t)1024 * 1024, 1024, 1024);
    add(wv_e, WTe + (size_t)2048 * 1024, 1024, 1024);
    add(aq1_w, WTa,          D_, AH_);
    add(aq2_w, WTa + 32768,  AH_, D_);
    add(ak1_w, WTa + 65536,  D_, AH_);
    add(ak2_w, WTa + 98304,  AH_, D_);
    add(av1_w, WTa + 131072, D_, AH_);
    add(av2_w, WTa + 163840, AH_, D_);
    ta.nseg = s;
    batch_transpose<<<dim3(blk), dim3(256), 0, stream>>>(ta);
  }

  // token-type scan + input gather
  build_inv<<<dim3(1), dim3(1024), 0, stream>>>(ttm, inv, cnt);
  gather_cast<<<dim3(NTOK), dim3(256), 0, stream>>>(x_text, x_ent, ttm, inv, xt_bf, xe_bf);

  // text QKV on compact rows (limit ntext_pad)
  G(xt_bf, WTb, nullptr, qkv_bf, NTOK, 6144, HID_, 0, 0, cnt + 1);
  // entity projection on compact rows (limit nent_pad)
  G(xe_bf, WTe, nullptr, e_all, NTOK, 3072, 1024, 0, 0, cnt + 3);

  // adapters (limit ceil128(nent*8))
  G(e_all,        WTa,          aq1_b, h1, NTOK * 8, AH_, D_, 1, 3072, cnt + 4);
  G(h1,           WTa + 32768,  aq2_b, qe, NTOK * 8, D_, AH_, 0, 0,    cnt + 4);
  G(e_all + 1024, WTa + 65536,  ak1_b, h1, NTOK * 8, AH_, D_, 1, 3072, cnt + 4);
  G(h1,           WTa + 98304,  ak2_b, ke, NTOK * 8, D_, AH_, 0, 0,    cnt + 4);
  G(e_all + 2048, WTa + 131072, av1_b, h1, NTOK * 8, AH_, D_, 1, 3072, cnt + 4);
  G(h1,           WTa + 163840, av2_b, ve, NTOK * 8, D_, AH_, 0, 0,    cnt + 4);

  // select + RoPE -> full-token Q/K bf16; V transpose
  select_rope_bf<<<dim3(NTOK), dim3(256), 0, stream>>>(
      qkv_bf, qe, ke, Q_bf, K_bf, ttm, inv, pid);
  vtrans_kernel<<<dim3(B_ * KVH_ * 32 * 4), dim3(256), 0, stream>>>(
      qkv_bf, ve, ttm, inv, VT_g);

  // weight transposes, batch 2 (into dead WTb region)
  {
    TArgs ta{}; int blk = 0, s = 0;
    auto add = [&](const float* W, u16* Wt, int K, int N) {
      ta.s[s] = {W, Wt, K, N, blk}; blk += (K >> 5) * (N >> 5); s++;
    };
    add(wo_t, WTo, HID_, HID_);
    add(ao1_w, WTao1, D_, AH_);
    add(ao2_w, WTao2, AH_, D_);
    add(wo_e, WToe, 1024, 1024);
    ta.nseg = s;
    batch_transpose<<<dim3(blk), dim3(256), 0, stream>>>(ta);
  }

  // MFMA flash attention -> compact bf16 (text rows [0,ntext), entity at ntext_pad)
  attn_mfma<<<dim3(B_ * H_ * 16), dim3(256), 0, stream>>>(
      Q_bf, K_bf, VT_g, attn_bf, ttm, inv, cnt);

  // entity output chain (compact)
  mean_heads_kernel<<<dim3(NTOK * 1024 / 256), dim3(256), 0, stream>>>(attn_bf, oe_bf, cnt);
  G(oe_bf, WTao1, ao1_b, h1o, NTOK * 8, AH_, D_, 1, 0, cnt + 4);
  G(h1o,   WTao2, ao2_b, oe2, NTOK * 8, D_, AH_, 0, 0, cnt + 4);
  G(oe2,   WToe, nullptr, ce_out, NTOK, 1024, 1024, 0, 0, cnt + 3);

  // text output projection (compact)
  G(attn_bf, WTo, nullptr, ct_out, NTOK, HID_, HID_, 0, 0, cnt + 1);

  // scatter to d_out with token-type masking
  scatter_out<<<dim3(NTOK), dim3(256), 0, stream>>>(
      ct_out, ce_out, ttm, inv, out_text, out_ent);
}

// Round 3
// 866.042 us; speedup vs baseline: 1.0150x; 1.0150x over previous
//
#include <hip/hip_runtime.h>
#include <cstdint>
#include <cstddef>

// Problem constants (reference: B=2,S=1024,HID=4096,H=32,D=128,KVH=8,EH=8,AH=256)
#define B_    2
#define S_    1024
#define HID_  4096
#define H_    32
#define D_    128
#define KVH_  8
#define EH_   8
#define AH_   256
#define NTOK  2048

typedef unsigned short u16;
typedef __attribute__((ext_vector_type(8))) short bf16x8;
typedef __attribute__((ext_vector_type(4))) float f32x4;
typedef const __attribute__((address_space(1))) void* gp_t;
typedef __attribute__((address_space(3))) void* lp_t;

__device__ __forceinline__ u16 f2bf(float f) {              // RNE f32->bf16
  unsigned u = __float_as_uint(f);
  return (u16)((u + 0x7FFF + ((u >> 16) & 1)) >> 16);
}
__device__ __forceinline__ float bf2f(u16 u) {
  return __uint_as_float((unsigned)u << 16);
}

// --------------- token-type scan: inv[] + counts (1 block) ---------------
// inv[t] = compact index within its type. cnt = {ntext, ntext_pad, nent,
// nent_pad, ceil128(nent*8), _}
__global__ __launch_bounds__(1024) void build_inv(
    const int* __restrict__ ttm, int* __restrict__ inv, int* __restrict__ cnt)
{
  __shared__ int a[NTOK], b[NTOK];
  const int t = threadIdx.x;
  for (int i = t; i < NTOK; i += 1024) a[i] = (ttm[i] != 1) ? 1 : 0;
  __syncthreads();
  int* src = a; int* dst = b;
  for (int off = 1; off < NTOK; off <<= 1) {
    for (int i = t; i < NTOK; i += 1024)
      dst[i] = src[i] + ((i >= off) ? src[i - off] : 0);
    __syncthreads();
    int* tmp = src; src = dst; dst = tmp;
  }
  for (int i = t; i < NTOK; i += 1024) {
    const int txt = (ttm[i] != 1);
    const int excl = src[i] - txt;
    inv[i] = txt ? excl : (i - excl);
  }
  if (t == 0) {
    const int ntext = src[NTOK - 1];
    const int nent = NTOK - ntext;
    cnt[0] = ntext;
    cnt[1] = (ntext + 127) & ~127;
    cnt[2] = nent;
    cnt[3] = (nent + 127) & ~127;
    cnt[4] = (nent * 8 + 127) & ~127;
  }
}

// --------------- gather inputs to per-type compact bf16 ---------------
__global__ __launch_bounds__(256) void gather_cast(
    const float* __restrict__ x_text, const float* __restrict__ x_ent,
    const int* __restrict__ ttm, const int* __restrict__ inv,
    u16* __restrict__ xt, u16* __restrict__ xe)
{
  const int tok = blockIdx.x;
  const int j = inv[tok];
  const int t = threadIdx.x;
  if (ttm[tok] != 1) {
    const float* src = x_text + (size_t)tok * HID_;
    u16* dst = xt + (size_t)j * HID_;
#pragma unroll
    for (int i = 0; i < 4; i++) {
      const int c = (i * 256 + t) * 4;
      const float4 v = *(const float4*)(src + c);
      ushort4 o; o.x = f2bf(v.x); o.y = f2bf(v.y); o.z = f2bf(v.z); o.w = f2bf(v.w);
      *(ushort4*)(dst + c) = o;
    }
  } else {
    const float* src = x_ent + (size_t)tok * 1024;
    u16* dst = xe + (size_t)j * 1024;
    const int c = t * 4;
    const float4 v = *(const float4*)(src + c);
    ushort4 o; o.x = f2bf(v.x); o.y = f2bf(v.y); o.z = f2bf(v.z); o.w = f2bf(v.w);
    *(ushort4*)(dst + c) = o;
  }
}

// ---------------- batched weight transpose+cast ----------------
struct TSeg { const float* W; u16* Wt; int K; int N; int blk0; };
struct TArgs { TSeg s[12]; int nseg; };

__global__ __launch_bounds__(256) void batch_transpose(TArgs args)
{
  int seg = 0;
#pragma unroll
  for (int i = 1; i < 12; i++)
    if (i < args.nseg && (int)blockIdx.x >= args.s[i].blk0) seg = i;
  const float* W = args.s[seg].W;
  u16* Wt = args.s[seg].Wt;
  const int K = args.s[seg].K, N = args.s[seg].N;
  const int local = blockIdx.x - args.s[seg].blk0;

  __shared__ float tle[32][33];
  const int tid = threadIdx.x;
  const int tx = tid & 31, ty = tid >> 5;
  const int nb = N >> 5;
  const int k0 = (local / nb) << 5;
  const int n0 = (local % nb) << 5;
#pragma unroll
  for (int r = 0; r < 32; r += 8)
    tle[ty + r][tx] = W[(size_t)(k0 + ty + r) * N + n0 + tx];
  __syncthreads();
#pragma unroll
  for (int r = 0; r < 32; r += 8)
    Wt[(size_t)(n0 + ty + r) * K + k0 + tx] = f2bf(tle[tx][ty + r]);
}

// --------------------- bf16 MFMA GEMM (128x128 tile, 4-deep pipelined) ---------------------
// C[M,N] bf16 = act(A @ Bt^T + bias). Early-exit rows >= *mlim.
// astride!=0: A row addressing = (row>>3)*astride + (row&7)*K
//
// K-loop: 4 LDS staging buffers; the ONLY vmcnt waits are the counted inline-asm
// ones (12 steady / 12-8-4-0 drain). Fragment loads are inline-asm ds_read_b128
// (no memory clobber) so SIInsertWaitcnts cannot see an LDS-read dependence on
// the pending global_load_lds DMA and insert a conservative vmcnt(0) -- which is
// what serialized rounds 0-2 at one exposed memory round trip per K-step.
// Rule #18: lgkmcnt(0) is followed by sched_barrier(0) so MFMAs can't hoist
// between the ds_reads and their wait.
__global__ __launch_bounds__(256) void gemm_bt_bf16(
    const u16* __restrict__ A, const u16* __restrict__ Bt,
    const float* __restrict__ bias, u16* __restrict__ C,
    int M, int N, int K, int act, int astride, const int* __restrict__ mlim)
{
  const int nTN = N >> 7;
  const int nTM = (int)gridDim.x / nTN;
  const int nwg = nTM * nTN;
  const int bid = (int)blockIdx.x;
  const int xcd = bid & 7, lix = bid >> 3;
  const int q = nwg >> 3, rr_ = nwg & 7;
  const int wgid = (xcd < rr_ ? xcd * (q + 1) : rr_ * (q + 1) + (xcd - rr_) * q) + lix;
  const int tcol = wgid / nTM;
  int trow = wgid - tcol * nTM;
  if ((nTM & 7) == 0) trow = ((trow & 7) * (nTM >> 3)) + (trow >> 3);
  const int m0 = trow << 7;
  if (mlim && m0 >= *mlim) return;
  const int n0 = tcol << 7;

  __shared__ __align__(16) char AsB[4][8192];
  __shared__ __align__(16) char BsB[4][8192];

  const int tid = threadIdx.x;
  const int wave = tid >> 6, lane = tid & 63;
  const int wm = ((wave >> 1) << 6);
  const int wn = ((wave & 1) << 6);
  const int l16 = lane & 15, lg = lane >> 4;

  const int ofs0 = (wave * 2) * 1024;
  const int flat0 = ofs0 + lane * 16;
  const int flat1 = flat0 + 1024;
  const int g0 = flat0 >> 11, r0 = (flat0 & 2047) >> 4;
  const int g1 = flat1 >> 11, r1 = (flat1 & 2047) >> 4;

  auto arow = [&](int row) -> size_t {
    return astride ? (size_t)(row >> 3) * astride + (size_t)(row & 7) * K
                   : (size_t)row * K;
  };
  const u16* a0 = A + arow(m0 + r0) + g0 * 8;
  const u16* a1 = A + arow(m0 + r1) + g1 * 8;
  const u16* b0 = Bt + (size_t)(n0 + r0) * K + g0 * 8;
  const u16* b1 = Bt + (size_t)(n0 + r1) * K + g1 * 8;

  f32x4 acc[4][4];
#pragma unroll
  for (int i = 0; i < 4; i++)
#pragma unroll
    for (int j = 0; j < 4; j++) acc[i][j] = (f32x4)0.f;

  const int nk = K >> 5;  // number of 32-wide K-tiles; nk >= 4 required

  // per-thread LDS byte addresses for asm ds_read
  const uint32_t asb_lds = (uint32_t)(size_t)(lp_t)(&AsB[0][0]);
  const uint32_t bsb_lds = (uint32_t)(size_t)(lp_t)(&BsB[0][0]);
  const uint32_t abase = asb_lds + (uint32_t)(lg * 2048 + (wm + l16) * 16);
  const uint32_t bbase = bsb_lds + (uint32_t)(lg * 2048 + (wn + l16) * 16);

  auto stage = [&](int buf) {
    __builtin_amdgcn_global_load_lds((gp_t)a0, (lp_t)(&AsB[buf][ofs0]),        16, 0, 0);
    __builtin_amdgcn_global_load_lds((gp_t)a1, (lp_t)(&AsB[buf][ofs0 + 1024]), 16, 0, 0);
    __builtin_amdgcn_global_load_lds((gp_t)b0, (lp_t)(&BsB[buf][ofs0]),        16, 0, 0);
    __builtin_amdgcn_global_load_lds((gp_t)b1, (lp_t)(&BsB[buf][ofs0 + 1024]), 16, 0, 0);
    a0 += 32; a1 += 32; b0 += 32; b1 += 32;
  };

  bf16x8 af[4], bv[4];
  auto ldrd = [&](int buf) {
    const uint32_t aA = abase + (uint32_t)buf * 8192u;
    const uint32_t aB = bbase + (uint32_t)buf * 8192u;
    asm volatile("ds_read_b128 %0, %1 offset:0"   : "=v"(af[0]) : "v"(aA));
    asm volatile("ds_read_b128 %0, %1 offset:256" : "=v"(af[1]) : "v"(aA));
    asm volatile("ds_read_b128 %0, %1 offset:512" : "=v"(af[2]) : "v"(aA));
    asm volatile("ds_read_b128 %0, %1 offset:768" : "=v"(af[3]) : "v"(aA));
    asm volatile("ds_read_b128 %0, %1 offset:0"   : "=v"(bv[0]) : "v"(aB));
    asm volatile("ds_read_b128 %0, %1 offset:256" : "=v"(bv[1]) : "v"(aB));
    asm volatile("ds_read_b128 %0, %1 offset:512" : "=v"(bv[2]) : "v"(aB));
    asm volatile("ds_read_b128 %0, %1 offset:768" : "=v"(bv[3]) : "v"(aB));
  };
  auto do_mfma = [&]() {
#pragma unroll
    for (int i = 0; i < 4; i++)
#pragma unroll
      for (int j = 0; j < 4; j++)
        acc[i][j] = __builtin_amdgcn_mfma_f32_16x16x32_bf16(af[i], bv[j], acc[i][j], 0, 0, 0);
  };

  // prologue: fill the 4-deep pipe (16 loads/wave outstanding)
#pragma unroll
  for (int t = 0; t < 4; t++) stage(t);

  int k = 0;
  // steady state: wait only for the oldest K-tile (12 loads = 3 tiles in flight)
  for (; k + 4 < nk; ++k) {
    asm volatile("s_waitcnt vmcnt(12)");
    __builtin_amdgcn_s_barrier();            // all waves' tile-k loads landed
    ldrd(k & 3);
    asm volatile("s_waitcnt lgkmcnt(0)");
    __builtin_amdgcn_s_barrier();            // all waves done reading buf k&3
    __builtin_amdgcn_sched_barrier(0);
    stage(k & 3);                            // refill freed buf with tile k+4
    __builtin_amdgcn_sched_barrier(0);
    do_mfma();                               // overlaps the in-flight loads
  }
  // drain: 4 remaining buffers, vmcnt 12 -> 8 -> 4 -> 0
  asm volatile("s_waitcnt vmcnt(12)");
  __builtin_amdgcn_s_barrier();
  ldrd(k & 3);
  asm volatile("s_waitcnt lgkmcnt(0)");
  __builtin_amdgcn_sched_barrier(0);
  do_mfma(); ++k;
  asm volatile("s_waitcnt vmcnt(8)");
  __builtin_amdgcn_s_barrier();
  ldrd(k & 3);
  asm volatile("s_waitcnt lgkmcnt(0)");
  __builtin_amdgcn_sched_barrier(0);
  do_mfma(); ++k;
  asm volatile("s_waitcnt vmcnt(4)");
  __builtin_amdgcn_s_barrier();
  ldrd(k & 3);
  asm volatile("s_waitcnt lgkmcnt(0)");
  __builtin_amdgcn_sched_barrier(0);
  do_mfma(); ++k;
  asm volatile("s_waitcnt vmcnt(0)");
  __builtin_amdgcn_s_barrier();
  ldrd(k & 3);
  asm volatile("s_waitcnt lgkmcnt(0)");
  __builtin_amdgcn_sched_barrier(0);
  do_mfma();

  // epilogue: C/D map col=lane&15, row=(lane>>4)*4+reg
#pragma unroll
  for (int i = 0; i < 4; i++) {
#pragma unroll
    for (int r = 0; r < 4; r++) {
      const int row = m0 + wm + 16 * i + lg * 4 + r;
#pragma unroll
      for (int j = 0; j < 4; j++) {
        const int col = n0 + wn + 16 * j + l16;
        float c = acc[i][j][r];
        if (bias) c += bias[col];
        if (act) c = 0.5f * c * (1.f + erff(c * 0.70710678118654752f));  // exact GELU
        C[(size_t)row * N + col] = f2bf(c);
      }
    }
  }
}

// ------------- select + RoPE -> bf16 Q (prescaled), bf16 K (full token index) -------------
// text: qkv compact bf16 [ntext][6144] (q @ h*128, k @ 4096+hk*128)
// entity: qe/ke compact bf16 [nent*8][128]
__global__ __launch_bounds__(256) void select_rope_bf(
    const u16* __restrict__ qkv, const u16* __restrict__ qe,
    const u16* __restrict__ ke, u16* __restrict__ Qb, u16* __restrict__ Kb,
    const int* __restrict__ ttm, const int* __restrict__ inv,
    const int* __restrict__ pid)
{
  __shared__ float cs[64], sn[64];
  const int token = blockIdx.x;
  const bool is_e = (ttm[token] == 1);
  const int j = inv[token];
  const int t = threadIdx.x;
  if (t < 64) {
    const float pos = (float)pid[token];
    const float iv = __expf(-((float)(2 * t) * (1.f / 128.f)) * 9.210340371976184f);
    const float f = pos * iv;
    cs[t] = cosf(f); sn[t] = sinf(f);
  }
  __syncthreads();
  const float scale = 0.08838834764831845f;  // 1/sqrt(128) folded into Q
  const u16* qrow = qkv + (size_t)j * 6144;

  for (int it = t; it < H_ * 64; it += 256) {
    const int h = it >> 6, i = it & 63;
    float x1, x2;
    if (is_e) {
      const size_t eb = ((size_t)j * 8 + (h & 7)) * D_;
      x1 = bf2f(qe[eb + i]); x2 = bf2f(qe[eb + i + 64]);
    } else {
      x1 = bf2f(qrow[h * 128 + i]); x2 = bf2f(qrow[h * 128 + i + 64]);
    }
    const size_t base = ((size_t)token * H_ + h) * D_;
    Qb[base + i]      = f2bf((x1 * cs[i] - x2 * sn[i]) * scale);
    Qb[base + i + 64] = f2bf((x2 * cs[i] + x1 * sn[i]) * scale);
  }
  for (int it = t; it < KVH_ * 64; it += 256) {
    const int h = it >> 6, i = it & 63;
    float x1, x2;
    if (is_e) {
      const size_t eb = ((size_t)j * 8 + h) * D_;
      x1 = bf2f(ke[eb + i]); x2 = bf2f(ke[eb + i + 64]);
    } else {
      x1 = bf2f(qrow[4096 + h * 128 + i]); x2 = bf2f(qrow[4096 + h * 128 + i + 64]);
    }
    const size_t base = ((size_t)token * KVH_ + h) * D_;
    Kb[base + i]      = f2bf(x1 * cs[i] - x2 * sn[i]);
    Kb[base + i + 64] = f2bf(x2 * cs[i] + x1 * sn[i]);
  }
}

// ---------- V select + transpose: VT[b][hk][d][s] bf16 ----------
__global__ __launch_bounds__(256) void vtrans_kernel(
    const u16* __restrict__ qkv, const u16* __restrict__ ve,
    const int* __restrict__ ttm, const int* __restrict__ inv,
    u16* __restrict__ VTg)
{
  __shared__ float t[32][33];
  const int dt = blockIdx.x & 3;
  const int st = (blockIdx.x >> 2) & 31;
  const int hk = (blockIdx.x >> 7) & 7;
  const int b  = blockIdx.x >> 10;
  const int s0 = st * 32, d0 = dt * 32;
  const int tx = threadIdx.x & 31, ty = threadIdx.x >> 5;
#pragma unroll
  for (int i = 0; i < 4; i++) {
    const int r = ty + 8 * i;
    const int tok = b * S_ + s0 + r;
    const int j = inv[tok];
    t[r][tx] = (ttm[tok] == 1)
        ? bf2f(ve[((size_t)j * 8 + hk) * D_ + d0 + tx])
        : bf2f(qkv[(size_t)j * 6144 + 5120 + hk * 128 + d0 + tx]);
  }
  __syncthreads();
#pragma unroll
  for (int i = 0; i < 4; i++) {
    const int rr = ty + 8 * i;
    VTg[((size_t)(b * KVH_ + hk) * D_ + d0 + rr) * S_ + s0 + tx] = f2bf(t[tx][rr]);
  }
}

// ------------------- MFMA causal GQA flash attention (compact output) -------------------
__global__ __launch_bounds__(256) void attn_mfma(
    const u16* __restrict__ Qb, const u16* __restrict__ Kb,
    const u16* __restrict__ VTg, u16* __restrict__ O,
    const int* __restrict__ ttm, const int* __restrict__ inv,
    const int* __restrict__ cnt)
{
  __shared__ __align__(16) u16 Ks[16 * 64 * 8];
  __shared__ __align__(16) u16 VTs[8 * 128 * 8];
  __shared__ __align__(16) float Ps[4][16 * 68];

  const int tid = threadIdx.x;
  const int wave = tid >> 6, lane = tid & 63;
  const int l16 = lane & 15, lg = lane >> 4;

  const int qtile = 15 - (blockIdx.x & 15);
  const int h = (blockIdx.x >> 4) & (H_ - 1);
  const int b = blockIdx.x >> 9;
  const int q0 = qtile * 64;
  const int hk = h & 7;
  const int qw = q0 + 16 * wave;
  const int qmax = qw + 15;

  bf16x8 qf[4];
  {
    const u16* qrow = Qb + ((size_t)(b * S_ + qw + l16) * H_ + h) * D_;
#pragma unroll
    for (int c = 0; c < 4; c++)
      qf[c] = *(const bf16x8*)(qrow + c * 32 + lg * 8);
  }

  f32x4 o[8];
#pragma unroll
  for (int nt = 0; nt < 8; nt++) o[nt] = (f32x4)0.f;
  float mrun[4] = {-1e30f, -1e30f, -1e30f, -1e30f};
  float lrun[4] = {0.f, 0.f, 0.f, 0.f};

  const int ntiles = qtile + 1;
  for (int t = 0; t < ntiles; t++) {
    const int k0 = t * 64;
    if (t) __syncthreads();
#pragma unroll
    for (int i = 0; i < 4; i++) {
      const int idx = i * 256 + tid;
      const int g = idx >> 6, key = idx & 63;
      *(bf16x8*)(Ks + idx * 8) =
          *(const bf16x8*)(Kb + ((size_t)(b * S_ + k0 + key) * KVH_ + hk) * D_ + g * 8);
    }
#pragma unroll
    for (int i = 0; i < 4; i++) {
      const int idx = i * 256 + tid;
      const int kg = idx >> 7, d = idx & 127;
      *(bf16x8*)(VTs + idx * 8) =
          *(const bf16x8*)(VTg + ((size_t)(b * KVH_ + hk) * D_ + d) * S_ + k0 + kg * 8);
    }
    __syncthreads();

    if (k0 > qmax) continue;

    f32x4 s[4];
#pragma unroll
    for (int c = 0; c < 4; c++) s[c] = (f32x4)0.f;
#pragma unroll
    for (int c = 0; c < 4; c++)
#pragma unroll
      for (int dc = 0; dc < 4; dc++) {
        const bf16x8 kf = *(const bf16x8*)(Ks + ((dc * 4 + lg) * 64 + c * 16 + l16) * 8);
        s[c] = __builtin_amdgcn_mfma_f32_16x16x32_bf16(qf[dc], kf, s[c], 0, 0, 0);
      }

    float p[4][4], alpha[4];
#pragma unroll
    for (int r = 0; r < 4; r++) {
      const int qg = qw + lg * 4 + r;
      float sv[4], mx = -1e30f;
#pragma unroll
      for (int c = 0; c < 4; c++) {
        const int kg_ = k0 + c * 16 + l16;
        float v = (kg_ <= qg) ? s[c][r] : -1e30f;
        sv[c] = v;
        mx = fmaxf(mx, v);
      }
#pragma unroll
      for (int off = 1; off < 16; off <<= 1)
        mx = fmaxf(mx, __shfl_xor(mx, off));
      const float mn = fmaxf(mrun[r], mx);
      alpha[r] = __expf(mrun[r] - mn);
      mrun[r] = mn;
      float rs = 0.f;
#pragma unroll
      for (int c = 0; c < 4; c++) { p[c][r] = __expf(sv[c] - mn); rs += p[c][r]; }
#pragma unroll
      for (int off = 1; off < 16; off <<= 1)
        rs += __shfl_xor(rs, off);
      lrun[r] = lrun[r] * alpha[r] + rs;
    }
#pragma unroll
    for (int nt = 0; nt < 8; nt++)
#pragma unroll
      for (int r = 0; r < 4; r++) o[nt][r] *= alpha[r];

    float* pw = Ps[wave];
#pragma unroll
    for (int c = 0; c < 4; c++)
#pragma unroll
      for (int r = 0; r < 4; r++)
        pw[(lg * 4 + r) * 68 + c * 16 + l16] = p[c][r];

    bf16x8 pa[2];
#pragma unroll
    for (int kc = 0; kc < 2; kc++) {
      const float* src = pw + l16 * 68 + kc * 32 + lg * 8;
      const float4 f0 = *(const float4*)(src);
      const float4 f1 = *(const float4*)(src + 4);
      bf16x8 v;
      v[0] = (short)f2bf(f0.x); v[1] = (short)f2bf(f0.y);
      v[2] = (short)f2bf(f0.z); v[3] = (short)f2bf(f0.w);
      v[4] = (short)f2bf(f1.x); v[5] = (short)f2bf(f1.y);
      v[6] = (short)f2bf(f1.z); v[7] = (short)f2bf(f1.w);
      pa[kc] = v;
    }

#pragma unroll
    for (int nt = 0; nt < 8; nt++)
#pragma unroll
      for (int kc = 0; kc < 2; kc++) {
        const bf16x8 vf = *(const bf16x8*)(VTs + ((kc * 4 + lg) * 128 + nt * 16 + l16) * 8);
        o[nt] = __builtin_amdgcn_mfma_f32_16x16x32_bf16(pa[kc], vf, o[nt], 0, 0, 0);
      }
  }

  // epilogue -> compact row: text j, entity ntext_pad + j
  const int ntext_pad = cnt[1];
#pragma unroll
  for (int r = 0; r < 4; r++) {
    const float inv_l = 1.f / lrun[r];
    const int tok = b * S_ + qw + lg * 4 + r;
    const int j = inv[tok];
    const int crow = (ttm[tok] != 1) ? j : (ntext_pad + j);
    u16* orow = O + (size_t)crow * (H_ * D_) + h * D_ + l16;
#pragma unroll
    for (int nt = 0; nt < 8; nt++)
      orow[nt * 16] = f2bf(o[nt][r] * inv_l);
  }
}

// ------------------- mean over 4 head-replicas (entity-compact) -------------------
__global__ __launch_bounds__(256) void mean_heads_kernel(
    const u16* __restrict__ attn, u16* __restrict__ oe, const int* __restrict__ cnt)
{
  const size_t idx = (size_t)blockIdx.x * 256 + threadIdx.x;
  const int j = (int)(idx >> 10);
  if (j >= cnt[2]) return;
  const int r = (int)(idx & 1023);
  const int h = r >> 7, d = r & 127;
  const u16* a = attn + (size_t)(cnt[1] + j) * (H_ * D_);
  const float s = 0.25f * (bf2f(a[h * D_ + d]) + bf2f(a[(8 + h) * D_ + d]) +
                           bf2f(a[(16 + h) * D_ + d]) + bf2f(a[(24 + h) * D_ + d]));
  oe[idx] = f2bf(s);
}

// ------------------- scatter compact outs -> d_out with type masking -------------------
__global__ __launch_bounds__(256) void scatter_out(
    const u16* __restrict__ ct, const u16* __restrict__ ce,
    const int* __restrict__ ttm, const int* __restrict__ inv,
    float* __restrict__ out_text, float* __restrict__ out_ent)
{
  const int tok = blockIdx.x;
  const bool is_e = (ttm[tok] == 1);
  const int j = inv[tok];
  const int t = threadIdx.x;
  float* ot = out_text + (size_t)tok * HID_;
#pragma unroll
  for (int i = 0; i < 4; i++) {
    const int c = (i * 256 + t) * 4;
    float4 v = make_float4(0.f, 0.f, 0.f, 0.f);
    if (!is_e) {
      const ushort4 u = *(const ushort4*)(ct + (size_t)j * HID_ + c);
      v.x = bf2f(u.x); v.y = bf2f(u.y); v.z = bf2f(u.z); v.w = bf2f(u.w);
    }
    *(float4*)(ot + c) = v;
  }
  float* oe_ = out_ent + (size_t)tok * 1024;
  {
    const int c = t * 4;
    float4 v = make_float4(0.f, 0.f, 0.f, 0.f);
    if (is_e) {
      const ushort4 u = *(const ushort4*)(ce + (size_t)j * 1024 + c);
      v.x = bf2f(u.x); v.y = bf2f(u.y); v.z = bf2f(u.z); v.w = bf2f(u.w);
    }
    *(float4*)(oe_ + c) = v;
  }
}

// ------------------------------- launcher -------------------------------
extern "C" void kernel_launch(void* const* d_in, const int* in_sizes, int n_in,
                              void* d_out, int out_size, void* d_ws, size_t ws_size,
                              hipStream_t stream)
{
  const float* x_text = (const float*)d_in[0];
  const float* x_ent  = (const float*)d_in[1];
  const float* wq_t   = (const float*)d_in[2];
  const float* wk_t   = (const float*)d_in[3];
  const float* wv_t   = (const float*)d_in[4];
  const float* wo_t   = (const float*)d_in[5];
  const float* wq_e   = (const float*)d_in[6];
  const float* wk_e   = (const float*)d_in[7];
  const float* wv_e   = (const float*)d_in[8];
  const float* wo_e   = (const float*)d_in[9];
  const float* aq1_w = (const float*)d_in[10]; const float* aq1_b = (const float*)d_in[11];
  const float* aq2_w = (const float*)d_in[12]; const float* aq2_b = (const float*)d_in[13];
  const float* ak1_w = (const float*)d_in[14]; const float* ak1_b = (const float*)d_in[15];
  const float* ak2_w = (const float*)d_in[16]; const float* ak2_b = (const float*)d_in[17];
  const float* av1_w = (const float*)d_in[18]; const float* av1_b = (const float*)d_in[19];
  const float* av2_w = (const float*)d_in[20]; const float* av2_b = (const float*)d_in[21];
  const float* ao1_w = (const float*)d_in[22]; const float* ao1_b = (const float*)d_in[23];
  const float* ao2_w = (const float*)d_in[24]; const float* ao2_b = (const float*)d_in[25];
  const int*   ttm   = (const int*)d_in[27];
  const int*   pid   = (const int*)d_in[28];

  float* out_text = (float*)d_out;                       // [2048,4096]
  float* out_ent  = out_text + (size_t)B_ * S_ * HID_;   // [2048,1024]

  // ---- workspace layout (bytes), peak ~132.5 MB (proven cap >= 142.6) ----
  char* w = (char*)d_ws;
  // R0 phase 1-2:
  u16*   qkv_bf = (u16*)(w + 0);             // 25,165,824  [2048][6144] compact text
  u16*   qe     = (u16*)(w + 25165824);      //  4,194,304  [2048*8][128] compact ent
  u16*   ke     = (u16*)(w + 29360128);      //  4,194,304
  u16*   ve     = (u16*)(w + 33554432);      //  4,194,304
  u16*   h1     = (u16*)(w + 37748736);      //  8,388,608  [16384][256]
  // R0 phase 3-4 overlays:
  u16*   attn_bf = (u16*)(w + 0);            // 17,825,792  [2176][4096] compact
  u16*   oe_bf   = (u16*)(w + 17825792);     //  4,194,304
  u16*   h1o     = (u16*)(w + 22020096);     //  8,388,608
  u16*   oe2     = (u16*)(w + 30408704);     //  4,194,304
  // R1: xt_bf -> e_all -> Q_bf -> ct_out
  u16*   xt_bf = (u16*)(w + 50331648);       // 16,777,216  [2048][4096] compact text
  u16*   e_all = (u16*)(w + 50331648);       // 12,582,912  [2048][3072] compact ent
  u16*   Q_bf  = (u16*)(w + 50331648);       // 16,777,216  full-token
  u16*   ct_out = (u16*)(w + 50331648);      // 16,777,216  wo_t compact C
  // R2: xe_bf -> K_bf -> ce_out
  u16*   xe_bf = (u16*)(w + 67108864);       //  4,194,304  [2048][1024] compact ent
  u16*   K_bf  = (u16*)(w + 67108864);       //  4,194,304  full-token
  u16*   ce_out = (u16*)(w + 67108864);      //  4,194,304  wo_e compact C
  // R3: WTb -> (phase 2+) WTo/WTao/WToe
  u16*   WTb   = (u16*)(w + 71303168);       // 50,331,648  [6144][4096]
  u16*   WTo   = (u16*)(w + 71303168);       // 33,554,432  [4096][4096]
  u16*   WTao1 = (u16*)(w + 104857600);      //     65,536
  u16*   WTao2 = (u16*)(w + 104923136);      //     65,536
  u16*   WToe  = (u16*)(w + 104988672);      //  2,097,152
  // R4/R5: entity weights
  u16*   WTe   = (u16*)(w + 121634816);      //  6,291,456  [3072][1024]
  u16*   WTa   = (u16*)(w + 127926272);      //    393,216  6 x [.][.]
  // R6/R7:
  u16*   VT_g  = (u16*)(w + 128319488);      //  4,194,304
  int*   inv   = (int*)(w + 132513792);      //      8,192
  int*   cnt   = (int*)(w + 132521984);      //         64

  auto G = [&](const u16* A, const u16* Bt, const float* bias, u16* C,
               int M, int N, int K, int act, int astride, const int* mlim) {
    gemm_bt_bf16<<<dim3((M >> 7) * (N >> 7)), dim3(256), 0, stream>>>(
        A, Bt, bias, C, M, N, K, act, astride, mlim);
  };

  // weight transposes, batch 1 (everything pre-attention)
  {
    TArgs ta{}; int blk = 0, s = 0;
    auto add = [&](const float* W, u16* Wt, int K, int N) {
      ta.s[s] = {W, Wt, K, N, blk}; blk += (K >> 5) * (N >> 5); s++;
    };
    add(wq_t, WTb, HID_, HID_);
    add(wk_t, WTb + (size_t)4096 * HID_, HID_, 1024);
    add(wv_t, WTb + (size_t)5120 * HID_, HID_, 1024);
    add(wq_e, WTe, 1024, 1024);
    add(wk_e, WTe + (size_t)1024 * 1024, 1024, 1024);
    add(wv_e, WTe + (size_t)2048 * 1024, 1024, 1024);
    add(aq1_w, WTa,          D_, AH_);
    add(aq2_w, WTa + 32768,  AH_, D_);
    add(ak1_w, WTa + 65536,  D_, AH_);
    add(ak2_w, WTa + 98304,  AH_, D_);
    add(av1_w, WTa + 131072, D_, AH_);
    add(av2_w, WTa + 163840, AH_, D_);
    ta.nseg = s;
    batch_transpose<<<dim3(blk), dim3(256), 0, stream>>>(ta);
  }

  // token-type scan + input gather
  build_inv<<<dim3(1), dim3(1024), 0, stream>>>(ttm, inv, cnt);
  gather_cast<<<dim3(NTOK), dim3(256), 0, stream>>>(x_text, x_ent, ttm, inv, xt_bf, xe_bf);

  // text QKV on compact rows (limit ntext_pad)
  G(xt_bf, WTb, nullptr, qkv_bf, NTOK, 6144, HID_, 0, 0, cnt + 1);
  // entity projection on compact rows (limit nent_pad)
  G(xe_bf, WTe, nullptr, e_all, NTOK, 3072, 1024, 0, 0, cnt + 3);

  // adapters (limit ceil128(nent*8))
  G(e_all,        WTa,          aq1_b, h1, NTOK * 8, AH_, D_, 1, 3072, cnt + 4);
  G(h1,           WTa + 32768,  aq2_b, qe, NTOK * 8, D_, AH_, 0, 0,    cnt + 4);
  G(e_all + 1024, WTa + 65536,  ak1_b, h1, NTOK * 8, AH_, D_, 1, 3072, cnt + 4);
  G(h1,           WTa + 98304,  ak2_b, ke, NTOK * 8, D_, AH_, 0, 0,    cnt + 4);
  G(e_all + 2048, WTa + 131072, av1_b, h1, NTOK * 8, AH_, D_, 1, 3072, cnt + 4);
  G(h1,           WTa + 163840, av2_b, ve, NTOK * 8, D_, AH_, 0, 0,    cnt + 4);

  // select + RoPE -> full-token Q/K bf16; V transpose
  select_rope_bf<<<dim3(NTOK), dim3(256), 0, stream>>>(
      qkv_bf, qe, ke, Q_bf, K_bf, ttm, inv, pid);
  vtrans_kernel<<<dim3(B_ * KVH_ * 32 * 4), dim3(256), 0, stream>>>(
      qkv_bf, ve, ttm, inv, VT_g);

  // weight transposes, batch 2 (into dead WTb region)
  {
    TArgs ta{}; int blk = 0, s = 0;
    auto add = [&](const float* W, u16* Wt, int K, int N) {
      ta.s[s] = {W, Wt, K, N, blk}; blk += (K >> 5) * (N >> 5); s++;
    };
    add(wo_t, WTo, HID_, HID_);
    add(ao1_w, WTao1, D_, AH_);
    add(ao2_w, WTao2, AH_, D_);
    add(wo_e, WToe, 1024, 1024);
    ta.nseg = s;
    batch_transpose<<<dim3(blk), dim3(256), 0, stream>>>(ta);
  }

  // MFMA flash attention -> compact bf16 (text rows [0,ntext), entity at ntext_pad)
  attn_mfma<<<dim3(B_ * H_ * 16), dim3(256), 0, stream>>>(
      Q_bf, K_bf, VT_g, attn_bf, ttm, inv, cnt);

  // entity output chain (compact)
  mean_heads_kernel<<<dim3(NTOK * 1024 / 256), dim3(256), 0, stream>>>(attn_bf, oe_bf, cnt);
  G(oe_bf, WTao1, ao1_b, h1o, NTOK * 8, AH_, D_, 1, 0, cnt + 4);
  G(h1o,   WTao2, ao2_b, oe2, NTOK * 8, D_, AH_, 0, 0, cnt + 4);
  G(oe2,   WToe, nullptr, ce_out, NTOK, 1024, 1024, 0, 0, cnt + 3);

  // text output projection (compact)
  G(attn_bf, WTo, nullptr, ct_out, NTOK, HID_, HID_, 0, 0, cnt + 1);

  // scatter to d_out with token-type masking
  scatter_out<<<dim3(NTOK), dim3(256), 0, stream>>>(
      ct_out, ce_out, ttm, inv, out_text, out_ent);
}

// Round 5
// 826.489 us; speedup vs baseline: 1.0636x; 1.0479x over previous
//
#include <hip/hip_runtime.h>
#include <cstdint>
#include <cstddef>

// Problem constants (reference: B=2,S=1024,HID=4096,H=32,D=128,KVH=8,EH=8,AH=256)
#define B_    2
#define S_    1024
#define HID_  4096
#define H_    32
#define D_    128
#define KVH_  8
#define EH_   8
#define AH_   256
#define NTOK  2048

typedef unsigned short u16;
typedef __attribute__((ext_vector_type(8))) short bf16x8;
typedef __attribute__((ext_vector_type(4))) float f32x4;
typedef const __attribute__((address_space(1))) void* gp_t;
typedef __attribute__((address_space(3))) void* lp_t;

__device__ __forceinline__ u16 f2bf(float f) {              // RNE f32->bf16
  unsigned u = __float_as_uint(f);
  return (u16)((u + 0x7FFF + ((u >> 16) & 1)) >> 16);
}
__device__ __forceinline__ float bf2f(u16 u) {
  return __uint_as_float((unsigned)u << 16);
}

// --------------- token-type scan: inv[] + counts (1 block) ---------------
// inv[t] = compact index within its type. cnt = {ntext, ntext_pad, nent,
// nent_pad, ceil128(nent*8), _}
__global__ __launch_bounds__(1024) void build_inv(
    const int* __restrict__ ttm, int* __restrict__ inv, int* __restrict__ cnt)
{
  __shared__ int a[NTOK], b[NTOK];
  const int t = threadIdx.x;
  for (int i = t; i < NTOK; i += 1024) a[i] = (ttm[i] != 1) ? 1 : 0;
  __syncthreads();
  int* src = a; int* dst = b;
  for (int off = 1; off < NTOK; off <<= 1) {
    for (int i = t; i < NTOK; i += 1024)
      dst[i] = src[i] + ((i >= off) ? src[i - off] : 0);
    __syncthreads();
    int* tmp = src; src = dst; dst = tmp;
  }
  for (int i = t; i < NTOK; i += 1024) {
    const int txt = (ttm[i] != 1);
    const int excl = src[i] - txt;
    inv[i] = txt ? excl : (i - excl);
  }
  if (t == 0) {
    const int ntext = src[NTOK - 1];
    const int nent = NTOK - ntext;
    cnt[0] = ntext;
    cnt[1] = (ntext + 127) & ~127;
    cnt[2] = nent;
    cnt[3] = (nent + 127) & ~127;
    cnt[4] = (nent * 8 + 127) & ~127;
  }
}

// --------------- gather inputs to per-type compact bf16 ---------------
__global__ __launch_bounds__(256) void gather_cast(
    const float* __restrict__ x_text, const float* __restrict__ x_ent,
    const int* __restrict__ ttm, const int* __restrict__ inv,
    u16* __restrict__ xt, u16* __restrict__ xe)
{
  const int tok = blockIdx.x;
  const int j = inv[tok];
  const int t = threadIdx.x;
  if (ttm[tok] != 1) {
    const float* src = x_text + (size_t)tok * HID_;
    u16* dst = xt + (size_t)j * HID_;
#pragma unroll
    for (int i = 0; i < 4; i++) {
      const int c = (i * 256 + t) * 4;
      const float4 v = *(const float4*)(src + c);
      ushort4 o; o.x = f2bf(v.x); o.y = f2bf(v.y); o.z = f2bf(v.z); o.w = f2bf(v.w);
      *(ushort4*)(dst + c) = o;
    }
  } else {
    const float* src = x_ent + (size_t)tok * 1024;
    u16* dst = xe + (size_t)j * 1024;
    const int c = t * 4;
    const float4 v = *(const float4*)(src + c);
    ushort4 o; o.x = f2bf(v.x); o.y = f2bf(v.y); o.z = f2bf(v.z); o.w = f2bf(v.w);
    *(ushort4*)(dst + c) = o;
  }
}

// ---------------- batched weight transpose+cast ----------------
struct TSeg { const float* W; u16* Wt; int K; int N; int blk0; };
struct TArgs { TSeg s[12]; int nseg; };

__global__ __launch_bounds__(256) void batch_transpose(TArgs args)
{
  int seg = 0;
#pragma unroll
  for (int i = 1; i < 12; i++)
    if (i < args.nseg && (int)blockIdx.x >= args.s[i].blk0) seg = i;
  const float* W = args.s[seg].W;
  u16* Wt = args.s[seg].Wt;
  const int K = args.s[seg].K, N = args.s[seg].N;
  const int local = blockIdx.x - args.s[seg].blk0;

  __shared__ float tle[32][33];
  const int tid = threadIdx.x;
  const int tx = tid & 31, ty = tid >> 5;
  const int nb = N >> 5;
  const int k0 = (local / nb) << 5;
  const int n0 = (local % nb) << 5;
#pragma unroll
  for (int r = 0; r < 32; r += 8)
    tle[ty + r][tx] = W[(size_t)(k0 + ty + r) * N + n0 + tx];
  __syncthreads();
#pragma unroll
  for (int r = 0; r < 32; r += 8)
    Wt[(size_t)(n0 + ty + r) * K + k0 + tx] = f2bf(tle[tx][ty + r]);
}

// --------------------- batched bf16 MFMA GEMM (m97 2-barrier structure) ---------------------
// Multiple INDEPENDENT GEMMs per dispatch via segment table -> restores the
// 3+ blocks/CU TLP regime m97's latency hiding relies on (rounds 1-3 proved
// intra-block pipelining is not the lever at 1-2 blocks/CU; occupancy is).
// Per segment: C[M,N] bf16 = act(A @ Bt^T + bias), early-exit rows >= cnt[mlimIdx].
// astride!=0: A row addressing = (row>>3)*astride + (row&7)*K.
// Each segment's block span is padded to %8 so the per-segment XCD swizzle
// stays aligned with the physical round-robin assignment.
// RACE AUDIT (r4 lesson): segments within one dispatch run CONCURRENTLY --
// no segment's output region may alias another segment's input region.
struct GSeg {
  const u16* A; const u16* Bt; const float* bias; u16* C;
  int N, K, act, astride, mlimIdx, blk0, nTM, nTN;
};
struct GArgs { GSeg s[4]; int nseg; };

__global__ __launch_bounds__(256) void gemm_batch(GArgs ga, const int* __restrict__ cnt)
{
  int seg = 0;
#pragma unroll
  for (int i = 1; i < 4; i++)
    if (i < ga.nseg && (int)blockIdx.x >= ga.s[i].blk0) seg = i;
  const GSeg sg = ga.s[seg];
  const int local = (int)blockIdx.x - sg.blk0;
  const int nTM = sg.nTM, nTN = sg.nTN;
  const int nwg = nTM * nTN;
  if (local >= nwg) return;                       // segment padding

  // bijective XCD swizzle (m204) + column-major tile order + row-stride perm
  const int xcd = local & 7, lix = local >> 3;
  const int q = nwg >> 3, rr_ = nwg & 7;
  const int wgid = (xcd < rr_ ? xcd * (q + 1) : rr_ * (q + 1) + (xcd - rr_) * q) + lix;
  const int tcol = wgid / nTM;
  int trow = wgid - tcol * nTM;
  if ((nTM & 7) == 0) trow = ((trow & 7) * (nTM >> 3)) + (trow >> 3);
  const int m0 = trow << 7;
  if (sg.mlimIdx >= 0 && m0 >= cnt[sg.mlimIdx]) return;
  const int n0 = tcol << 7;

  const int N = sg.N, K = sg.K;
  const u16* __restrict__ A = sg.A;
  const u16* __restrict__ Bt = sg.Bt;

  __shared__ __align__(16) char AsB[8192];
  __shared__ __align__(16) char BsB[8192];

  const int tid = threadIdx.x;
  const int wave = tid >> 6, lane = tid & 63;
  const int wm = ((wave >> 1) << 6);
  const int wn = ((wave & 1) << 6);
  const int l16 = lane & 15, lg = lane >> 4;

  const int ofs0 = (wave * 2) * 1024;
  const int flat0 = ofs0 + lane * 16;
  const int flat1 = flat0 + 1024;
  const int g0 = flat0 >> 11, r0 = (flat0 & 2047) >> 4;
  const int g1 = flat1 >> 11, r1 = (flat1 & 2047) >> 4;

  auto arow = [&](int row) -> size_t {
    return sg.astride ? (size_t)(row >> 3) * sg.astride + (size_t)(row & 7) * K
                      : (size_t)row * K;
  };
  const u16* a0 = A + arow(m0 + r0) + g0 * 8;
  const u16* a1 = A + arow(m0 + r1) + g1 * 8;
  const u16* b0 = Bt + (size_t)(n0 + r0) * K + g0 * 8;
  const u16* b1 = Bt + (size_t)(n0 + r1) * K + g1 * 8;

  f32x4 acc[4][4];
#pragma unroll
  for (int i = 0; i < 4; i++)
#pragma unroll
    for (int j = 0; j < 4; j++) acc[i][j] = (f32x4)0.f;

  for (int k0 = 0; k0 < K; k0 += 32) {
    if (k0) __syncthreads();
    __builtin_amdgcn_global_load_lds((gp_t)a0, (lp_t)(AsB + ofs0),        16, 0, 0);
    __builtin_amdgcn_global_load_lds((gp_t)a1, (lp_t)(AsB + ofs0 + 1024), 16, 0, 0);
    __builtin_amdgcn_global_load_lds((gp_t)b0, (lp_t)(BsB + ofs0),        16, 0, 0);
    __builtin_amdgcn_global_load_lds((gp_t)b1, (lp_t)(BsB + ofs0 + 1024), 16, 0, 0);
    a0 += 32; a1 += 32; b0 += 32; b1 += 32;
    __syncthreads();

    bf16x8 af[4], bv[4];
#pragma unroll
    for (int i = 0; i < 4; i++)
      af[i] = *(const bf16x8*)(AsB + lg * 2048 + (wm + 16 * i + l16) * 16);
#pragma unroll
    for (int j = 0; j < 4; j++)
      bv[j] = *(const bf16x8*)(BsB + lg * 2048 + (wn + 16 * j + l16) * 16);
#pragma unroll
    for (int i = 0; i < 4; i++)
#pragma unroll
      for (int j = 0; j < 4; j++)
        acc[i][j] = __builtin_amdgcn_mfma_f32_16x16x32_bf16(af[i], bv[j], acc[i][j], 0, 0, 0);
  }

  // epilogue: C/D map col=lane&15, row=(lane>>4)*4+reg
#pragma unroll
  for (int i = 0; i < 4; i++) {
#pragma unroll
    for (int r = 0; r < 4; r++) {
      const int row = m0 + wm + 16 * i + lg * 4 + r;
#pragma unroll
      for (int j = 0; j < 4; j++) {
        const int col = n0 + wn + 16 * j + l16;
        float c = acc[i][j][r];
        if (sg.bias) c += sg.bias[col];
        if (sg.act) c = 0.5f * c * (1.f + erff(c * 0.70710678118654752f));  // exact GELU
        sg.C[(size_t)row * N + col] = f2bf(c);
      }
    }
  }
}

// ------------- select + RoPE -> bf16 Q (prescaled), bf16 K (full token index) -------------
// text: qkv compact bf16 [ntext][6144] (q @ h*128, k @ 4096+hk*128)
// entity: qe/ke compact bf16 [nent*8][128]
__global__ __launch_bounds__(256) void select_rope_bf(
    const u16* __restrict__ qkv, const u16* __restrict__ qe,
    const u16* __restrict__ ke, u16* __restrict__ Qb, u16* __restrict__ Kb,
    const int* __restrict__ ttm, const int* __restrict__ inv,
    const int* __restrict__ pid)
{
  __shared__ float cs[64], sn[64];
  const int token = blockIdx.x;
  const bool is_e = (ttm[token] == 1);
  const int j = inv[token];
  const int t = threadIdx.x;
  if (t < 64) {
    const float pos = (float)pid[token];
    const float iv = __expf(-((float)(2 * t) * (1.f / 128.f)) * 9.210340371976184f);
    const float f = pos * iv;
    cs[t] = cosf(f); sn[t] = sinf(f);
  }
  __syncthreads();
  const float scale = 0.08838834764831845f;  // 1/sqrt(128) folded into Q
  const u16* qrow = qkv + (size_t)j * 6144;

  for (int it = t; it < H_ * 64; it += 256) {
    const int h = it >> 6, i = it & 63;
    float x1, x2;
    if (is_e) {
      const size_t eb = ((size_t)j * 8 + (h & 7)) * D_;
      x1 = bf2f(qe[eb + i]); x2 = bf2f(qe[eb + i + 64]);
    } else {
      x1 = bf2f(qrow[h * 128 + i]); x2 = bf2f(qrow[h * 128 + i + 64]);
    }
    const size_t base = ((size_t)token * H_ + h) * D_;
    Qb[base + i]      = f2bf((x1 * cs[i] - x2 * sn[i]) * scale);
    Qb[base + i + 64] = f2bf((x2 * cs[i] + x1 * sn[i]) * scale);
  }
  for (int it = t; it < KVH_ * 64; it += 256) {
    const int h = it >> 6, i = it & 63;
    float x1, x2;
    if (is_e) {
      const size_t eb = ((size_t)j * 8 + h) * D_;
      x1 = bf2f(ke[eb + i]); x2 = bf2f(ke[eb + i + 64]);
    } else {
      x1 = bf2f(qrow[4096 + h * 128 + i]); x2 = bf2f(qrow[4096 + h * 128 + i + 64]);
    }
    const size_t base = ((size_t)token * KVH_ + h) * D_;
    Kb[base + i]      = f2bf(x1 * cs[i] - x2 * sn[i]);
    Kb[base + i + 64] = f2bf(x2 * cs[i] + x1 * sn[i]);
  }
}

// ---------- V select + transpose: VT[b][hk][d][s] bf16 ----------
__global__ __launch_bounds__(256) void vtrans_kernel(
    const u16* __restrict__ qkv, const u16* __restrict__ ve,
    const int* __restrict__ ttm, const int* __restrict__ inv,
    u16* __restrict__ VTg)
{
  __shared__ float t[32][33];
  const int dt = blockIdx.x & 3;
  const int st = (blockIdx.x >> 2) & 31;
  const int hk = (blockIdx.x >> 7) & 7;
  const int b  = blockIdx.x >> 10;
  const int s0 = st * 32, d0 = dt * 32;
  const int tx = threadIdx.x & 31, ty = threadIdx.x >> 5;
#pragma unroll
  for (int i = 0; i < 4; i++) {
    const int r = ty + 8 * i;
    const int tok = b * S_ + s0 + r;
    const int j = inv[tok];
    t[r][tx] = (ttm[tok] == 1)
        ? bf2f(ve[((size_t)j * 8 + hk) * D_ + d0 + tx])
        : bf2f(qkv[(size_t)j * 6144 + 5120 + hk * 128 + d0 + tx]);
  }
  __syncthreads();
#pragma unroll
  for (int i = 0; i < 4; i++) {
    const int rr = ty + 8 * i;
    VTg[((size_t)(b * KVH_ + hk) * D_ + d0 + rr) * S_ + s0 + tx] = f2bf(t[tx][rr]);
  }
}

// ------------------- MFMA causal GQA flash attention (compact output) -------------------
__global__ __launch_bounds__(256) void attn_mfma(
    const u16* __restrict__ Qb, const u16* __restrict__ Kb,
    const u16* __restrict__ VTg, u16* __restrict__ O,
    const int* __restrict__ ttm, const int* __restrict__ inv,
    const int* __restrict__ cnt)
{
  __shared__ __align__(16) u16 Ks[16 * 64 * 8];
  __shared__ __align__(16) u16 VTs[8 * 128 * 8];
  __shared__ __align__(16) float Ps[4][16 * 68];

  const int tid = threadIdx.x;
  const int wave = tid >> 6, lane = tid & 63;
  const int l16 = lane & 15, lg = lane >> 4;

  const int qtile = 15 - (blockIdx.x & 15);
  const int h = (blockIdx.x >> 4) & (H_ - 1);
  const int b = blockIdx.x >> 9;
  const int q0 = qtile * 64;
  const int hk = h & 7;
  const int qw = q0 + 16 * wave;
  const int qmax = qw + 15;

  bf16x8 qf[4];
  {
    const u16* qrow = Qb + ((size_t)(b * S_ + qw + l16) * H_ + h) * D_;
#pragma unroll
    for (int c = 0; c < 4; c++)
      qf[c] = *(const bf16x8*)(qrow + c * 32 + lg * 8);
  }

  f32x4 o[8];
#pragma unroll
  for (int nt = 0; nt < 8; nt++) o[nt] = (f32x4)0.f;
  float mrun[4] = {-1e30f, -1e30f, -1e30f, -1e30f};
  float lrun[4] = {0.f, 0.f, 0.f, 0.f};

  const int ntiles = qtile + 1;
  for (int t = 0; t < ntiles; t++) {
    const int k0 = t * 64;
    if (t) __syncthreads();
#pragma unroll
    for (int i = 0; i < 4; i++) {
      const int idx = i * 256 + tid;
      const int g = idx >> 6, key = idx & 63;
      *(bf16x8*)(Ks + idx * 8) =
          *(const bf16x8*)(Kb + ((size_t)(b * S_ + k0 + key) * KVH_ + hk) * D_ + g * 8);
    }
#pragma unroll
    for (int i = 0; i < 4; i++) {
      const int idx = i * 256 + tid;
      const int kg = idx >> 7, d = idx & 127;
      *(bf16x8*)(VTs + idx * 8) =
          *(const bf16x8*)(VTg + ((size_t)(b * KVH_ + hk) * D_ + d) * S_ + k0 + kg * 8);
    }
    __syncthreads();

    if (k0 > qmax) continue;

    f32x4 s[4];
#pragma unroll
    for (int c = 0; c < 4; c++) s[c] = (f32x4)0.f;
#pragma unroll
    for (int c = 0; c < 4; c++)
#pragma unroll
      for (int dc = 0; dc < 4; dc++) {
        const bf16x8 kf = *(const bf16x8*)(Ks + ((dc * 4 + lg) * 64 + c * 16 + l16) * 8);
        s[c] = __builtin_amdgcn_mfma_f32_16x16x32_bf16(qf[dc], kf, s[c], 0, 0, 0);
      }

    float p[4][4], alpha[4];
#pragma unroll
    for (int r = 0; r < 4; r++) {
      const int qg = qw + lg * 4 + r;
      float sv[4], mx = -1e30f;
#pragma unroll
      for (int c = 0; c < 4; c++) {
        const int kg_ = k0 + c * 16 + l16;
        float v = (kg_ <= qg) ? s[c][r] : -1e30f;
        sv[c] = v;
        mx = fmaxf(mx, v);
      }
#pragma unroll
      for (int off = 1; off < 16; off <<= 1)
        mx = fmaxf(mx, __shfl_xor(mx, off));
      const float mn = fmaxf(mrun[r], mx);
      alpha[r] = __expf(mrun[r] - mn);
      mrun[r] = mn;
      float rs = 0.f;
#pragma unroll
      for (int c = 0; c < 4; c++) { p[c][r] = __expf(sv[c] - mn); rs += p[c][r]; }
#pragma unroll
      for (int off = 1; off < 16; off <<= 1)
        rs += __shfl_xor(rs, off);
      lrun[r] = lrun[r] * alpha[r] + rs;
    }
#pragma unroll
    for (int nt = 0; nt < 8; nt++)
#pragma unroll
      for (int r = 0; r < 4; r++) o[nt][r] *= alpha[r];

    float* pw = Ps[wave];
#pragma unroll
    for (int c = 0; c < 4; c++)
#pragma unroll
      for (int r = 0; r < 4; r++)
        pw[(lg * 4 + r) * 68 + c * 16 + l16] = p[c][r];

    bf16x8 pa[2];
#pragma unroll
    for (int kc = 0; kc < 2; kc++) {
      const float* src = pw + l16 * 68 + kc * 32 + lg * 8;
      const float4 f0 = *(const float4*)(src);
      const float4 f1 = *(const float4*)(src + 4);
      bf16x8 v;
      v[0] = (short)f2bf(f0.x); v[1] = (short)f2bf(f0.y);
      v[2] = (short)f2bf(f0.z); v[3] = (short)f2bf(f0.w);
      v[4] = (short)f2bf(f1.x); v[5] = (short)f2bf(f1.y);
      v[6] = (short)f2bf(f1.z); v[7] = (short)f2bf(f1.w);
      pa[kc] = v;
    }

#pragma unroll
    for (int nt = 0; nt < 8; nt++)
#pragma unroll
      for (int kc = 0; kc < 2; kc++) {
        const bf16x8 vf = *(const bf16x8*)(VTs + ((kc * 4 + lg) * 128 + nt * 16 + l16) * 8);
        o[nt] = __builtin_amdgcn_mfma_f32_16x16x32_bf16(pa[kc], vf, o[nt], 0, 0, 0);
      }
  }

  // epilogue -> compact row: text j, entity ntext_pad + j
  const int ntext_pad = cnt[1];
#pragma unroll
  for (int r = 0; r < 4; r++) {
    const float inv_l = 1.f / lrun[r];
    const int tok = b * S_ + qw + lg * 4 + r;
    const int j = inv[tok];
    const int crow = (ttm[tok] != 1) ? j : (ntext_pad + j);
    u16* orow = O + (size_t)crow * (H_ * D_) + h * D_ + l16;
#pragma unroll
    for (int nt = 0; nt < 8; nt++)
      orow[nt * 16] = f2bf(o[nt][r] * inv_l);
  }
}

// ------------------- mean over 4 head-replicas (entity-compact) -------------------
__global__ __launch_bounds__(256) void mean_heads_kernel(
    const u16* __restrict__ attn, u16* __restrict__ oe, const int* __restrict__ cnt)
{
  const size_t idx = (size_t)blockIdx.x * 256 + threadIdx.x;
  const int j = (int)(idx >> 10);
  if (j >= cnt[2]) return;
  const int r = (int)(idx & 1023);
  const int h = r >> 7, d = r & 127;
  const u16* a = attn + (size_t)(cnt[1] + j) * (H_ * D_);
  const float s = 0.25f * (bf2f(a[h * D_ + d]) + bf2f(a[(8 + h) * D_ + d]) +
                           bf2f(a[(16 + h) * D_ + d]) + bf2f(a[(24 + h) * D_ + d]));
  oe[idx] = f2bf(s);
}

// ------------------- scatter compact outs -> d_out with type masking -------------------
__global__ __launch_bounds__(256) void scatter_out(
    const u16* __restrict__ ct, const u16* __restrict__ ce,
    const int* __restrict__ ttm, const int* __restrict__ inv,
    float* __restrict__ out_text, float* __restrict__ out_ent)
{
  const int tok = blockIdx.x;
  const bool is_e = (ttm[tok] == 1);
  const int j = inv[tok];
  const int t = threadIdx.x;
  float* ot = out_text + (size_t)tok * HID_;
#pragma unroll
  for (int i = 0; i < 4; i++) {
    const int c = (i * 256 + t) * 4;
    float4 v = make_float4(0.f, 0.f, 0.f, 0.f);
    if (!is_e) {
      const ushort4 u = *(const ushort4*)(ct + (size_t)j * HID_ + c);
      v.x = bf2f(u.x); v.y = bf2f(u.y); v.z = bf2f(u.z); v.w = bf2f(u.w);
    }
    *(float4*)(ot + c) = v;
  }
  float* oe_ = out_ent + (size_t)tok * 1024;
  {
    const int c = t * 4;
    float4 v = make_float4(0.f, 0.f, 0.f, 0.f);
    if (is_e) {
      const ushort4 u = *(const ushort4*)(ce + (size_t)j * 1024 + c);
      v.x = bf2f(u.x); v.y = bf2f(u.y); v.z = bf2f(u.z); v.w = bf2f(u.w);
    }
    *(float4*)(oe_ + c) = v;
  }
}

// ------------------------------- launcher -------------------------------
extern "C" void kernel_launch(void* const* d_in, const int* in_sizes, int n_in,
                              void* d_out, int out_size, void* d_ws, size_t ws_size,
                              hipStream_t stream)
{
  const float* x_text = (const float*)d_in[0];
  const float* x_ent  = (const float*)d_in[1];
  const float* wq_t   = (const float*)d_in[2];
  const float* wk_t   = (const float*)d_in[3];
  const float* wv_t   = (const float*)d_in[4];
  const float* wo_t   = (const float*)d_in[5];
  const float* wq_e   = (const float*)d_in[6];
  const float* wk_e   = (const float*)d_in[7];
  const float* wv_e   = (const float*)d_in[8];
  const float* wo_e   = (const float*)d_in[9];
  const float* aq1_w = (const float*)d_in[10]; const float* aq1_b = (const float*)d_in[11];
  const float* aq2_w = (const float*)d_in[12]; const float* aq2_b = (const float*)d_in[13];
  const float* ak1_w = (const float*)d_in[14]; const float* ak1_b = (const float*)d_in[15];
  const float* ak2_w = (const float*)d_in[16]; const float* ak2_b = (const float*)d_in[17];
  const float* av1_w = (const float*)d_in[18]; const float* av1_b = (const float*)d_in[19];
  const float* av2_w = (const float*)d_in[20]; const float* av2_b = (const float*)d_in[21];
  const float* ao1_w = (const float*)d_in[22]; const float* ao1_b = (const float*)d_in[23];
  const float* ao2_w = (const float*)d_in[24]; const float* ao2_b = (const float*)d_in[25];
  const int*   ttm   = (const int*)d_in[27];
  const int*   pid   = (const int*)d_in[28];

  float* out_text = (float*)d_out;                       // [2048,4096]
  float* out_ent  = out_text + (size_t)B_ * S_ * HID_;   // [2048,1024]

  // ---- workspace layout (bytes), peak ~132.5 MB ----
  // Liveness audit (r4 race fix): e_all now lives at 25,165,824 over the
  // qe/ke/ve span (exact 12.58 MB fit). e_all live [batchA.W -> batchB.R];
  // qe/ke/ve live [batchC.W -> select_rope/vtrans.R] -- phase-disjoint.
  // This removes the r4 race where e_all (at 50.3MB) was written by batch A
  // seg-1 while seg-0 concurrently read xt_bf at the same address.
  char* w = (char*)d_ws;
  // R0 phase 1-2:
  u16*   qkv_bf = (u16*)(w + 0);             // 25,165,824  [2048][6144] compact text
  u16*   e_all  = (u16*)(w + 25165824);      // 12,582,912  [2048][3072] compact ent (batch A-B)
  u16*   qe     = (u16*)(w + 25165824);      //  4,194,304  [2048*8][128] (batch C+)
  u16*   ke     = (u16*)(w + 29360128);      //  4,194,304
  u16*   ve     = (u16*)(w + 33554432);      //  4,194,304
  u16*   h1q    = (u16*)(w + 37748736);      //  8,388,608  [16384][256]
  // R0 phase 3-4 overlays:
  u16*   attn_bf = (u16*)(w + 0);            // 17,825,792  [2176][4096] compact
  u16*   oe_bf   = (u16*)(w + 17825792);     //  4,194,304
  u16*   h1o     = (u16*)(w + 22020096);     //  8,388,608
  u16*   oe2     = (u16*)(w + 30408704);     //  4,194,304
  // R1: xt_bf -> Q_bf -> ct_out
  u16*   xt_bf = (u16*)(w + 50331648);       // 16,777,216  [2048][4096] compact text
  u16*   Q_bf  = (u16*)(w + 50331648);       // 16,777,216  full-token
  u16*   ct_out = (u16*)(w + 50331648);      // 16,777,216  wo_t compact C
  // h1k lives in the dead {tail of xt_bf + xe_bf} span during adapters
  u16*   h1k   = (u16*)(w + 62914560);       //  8,388,608  (62.9MB..71.3MB)
  // R2: xe_bf -> K_bf -> ce_out
  u16*   xe_bf = (u16*)(w + 67108864);       //  4,194,304  [2048][1024] compact ent
  u16*   K_bf  = (u16*)(w + 67108864);       //  4,194,304  full-token
  u16*   ce_out = (u16*)(w + 67108864);      //  4,194,304  wo_e compact C
  // R3: WTb -> (phase 2+) h1v -> WTo/WTao/WToe
  u16*   WTb   = (u16*)(w + 71303168);       // 50,331,648  [6144][4096]
  u16*   h1v   = (u16*)(w + 71303168);       //  8,388,608  (over dead WTb, pre-WTo)
  u16*   WTo   = (u16*)(w + 71303168);       // 33,554,432  [4096][4096]
  u16*   WTao1 = (u16*)(w + 104857600);      //     65,536
  u16*   WTao2 = (u16*)(w + 104923136);      //     65,536
  u16*   WToe  = (u16*)(w + 104988672);      //  2,097,152
  // R4/R5: entity weights
  u16*   WTe   = (u16*)(w + 121634816);      //  6,291,456  [3072][1024]
  u16*   WTa   = (u16*)(w + 127926272);      //    393,216  6 x [.][.]
  // R6/R7:
  u16*   VT_g  = (u16*)(w + 128319488);      //  4,194,304
  int*   inv   = (int*)(w + 132513792);      //      8,192
  int*   cnt   = (int*)(w + 132521984);      //         64

  // batched GEMM launcher: segments padded to %8 blocks
  struct B {
    GArgs ga{}; int blk = 0;
    void add(const u16* A, const u16* Bt, const float* bias, u16* C,
             int M, int N, int K, int act, int astride, int mlimIdx) {
      GSeg& s = ga.s[ga.nseg++];
      s = {A, Bt, bias, C, N, K, act, astride, mlimIdx, blk, M >> 7, N >> 7};
      blk += ((s.nTM * s.nTN) + 7) & ~7;
    }
  };
  auto launch = [&](B& b) {
    gemm_batch<<<dim3(b.blk), dim3(256), 0, stream>>>(b.ga, cnt);
  };

  // weight transposes, batch 1 (everything pre-attention)
  {
    TArgs ta{}; int blk = 0, s = 0;
    auto add = [&](const float* W, u16* Wt, int K, int N) {
      ta.s[s] = {W, Wt, K, N, blk}; blk += (K >> 5) * (N >> 5); s++;
    };
    add(wq_t, WTb, HID_, HID_);
    add(wk_t, WTb + (size_t)4096 * HID_, HID_, 1024);
    add(wv_t, WTb + (size_t)5120 * HID_, HID_, 1024);
    add(wq_e, WTe, 1024, 1024);
    add(wk_e, WTe + (size_t)1024 * 1024, 1024, 1024);
    add(wv_e, WTe + (size_t)2048 * 1024, 1024, 1024);
    add(aq1_w, WTa,          D_, AH_);
    add(aq2_w, WTa + 32768,  AH_, D_);
    add(ak1_w, WTa + 65536,  D_, AH_);
    add(ak2_w, WTa + 98304,  AH_, D_);
    add(av1_w, WTa + 131072, D_, AH_);
    add(av2_w, WTa + 163840, AH_, D_);
    ta.nseg = s;
    batch_transpose<<<dim3(blk), dim3(256), 0, stream>>>(ta);
  }

  // token-type scan + input gather
  build_inv<<<dim3(1), dim3(1024), 0, stream>>>(ttm, inv, cnt);
  gather_cast<<<dim3(NTOK), dim3(256), 0, stream>>>(x_text, x_ent, ttm, inv, xt_bf, xe_bf);

  // batch A: text QKV || entity projection (independent; disjoint regions)
  //   seg0 R:{xt_bf,WTb} W:{qkv_bf}   seg1 R:{xe_bf,WTe} W:{e_all@25.2MB}
  {
    B b;
    b.add(xt_bf, WTb, nullptr, qkv_bf, NTOK, 6144, HID_, 0, 0, 1);
    b.add(xe_bf, WTe, nullptr, e_all, NTOK, 3072, 1024, 0, 0, 3);
    launch(b);
  }
  // batch B: adapter layer-1 q||k||v (share input e_all; outputs disjoint)
  {
    B b;
    b.add(e_all,        WTa,          aq1_b, h1q, NTOK * 8, AH_, D_, 1, 3072, 4);
    b.add(e_all + 1024, WTa + 65536,  ak1_b, h1k, NTOK * 8, AH_, D_, 1, 3072, 4);
    b.add(e_all + 2048, WTa + 131072, av1_b, h1v, NTOK * 8, AH_, D_, 1, 3072, 4);
    launch(b);
  }
  // batch C: adapter layer-2 q||k||v (write qe/ke/ve over dead e_all)
  {
    B b;
    b.add(h1q, WTa + 32768,  aq2_b, qe, NTOK * 8, D_, AH_, 0, 0, 4);
    b.add(h1k, WTa + 98304,  ak2_b, ke, NTOK * 8, D_, AH_, 0, 0, 4);
    b.add(h1v, WTa + 163840, av2_b, ve, NTOK * 8, D_, AH_, 0, 0, 4);
    launch(b);
  }

  // select + RoPE -> full-token Q/K bf16; V transpose
  select_rope_bf<<<dim3(NTOK), dim3(256), 0, stream>>>(
      qkv_bf, qe, ke, Q_bf, K_bf, ttm, inv, pid);
  vtrans_kernel<<<dim3(B_ * KVH_ * 32 * 4), dim3(256), 0, stream>>>(
      qkv_bf, ve, ttm, inv, VT_g);

  // weight transposes, batch 2 (into dead WTb region; h1v already consumed)
  {
    TArgs ta{}; int blk = 0, s = 0;
    auto add = [&](const float* W, u16* Wt, int K, int N) {
      ta.s[s] = {W, Wt, K, N, blk}; blk += (K >> 5) * (N >> 5); s++;
    };
    add(wo_t, WTo, HID_, HID_);
    add(ao1_w, WTao1, D_, AH_);
    add(ao2_w, WTao2, AH_, D_);
    add(wo_e, WToe, 1024, 1024);
    ta.nseg = s;
    batch_transpose<<<dim3(blk), dim3(256), 0, stream>>>(ta);
  }

  // MFMA flash attention -> compact bf16 (text rows [0,ntext), entity at ntext_pad)
  attn_mfma<<<dim3(B_ * H_ * 16), dim3(256), 0, stream>>>(
      Q_bf, K_bf, VT_g, attn_bf, ttm, inv, cnt);

  // entity mean, then batch D: wo_t || adapter-out layer-1 (disjoint regions)
  //   seg0 R:{attn_bf 0-17.8M, WTo} W:{ct_out 50.3-67.1M}
  //   seg1 R:{oe_bf 17.8-22.0M, WTao1} W:{h1o 22.0-30.4M}
  mean_heads_kernel<<<dim3(NTOK * 1024 / 256), dim3(256), 0, stream>>>(attn_bf, oe_bf, cnt);
  {
    B b;
    b.add(attn_bf, WTo, nullptr, ct_out, NTOK, HID_, HID_, 0, 0, 1);
    b.add(oe_bf, WTao1, ao1_b, h1o, NTOK * 8, AH_, D_, 1, 0, 4);
    launch(b);
  }
  // serial tail of entity chain
  {
    B b; b.add(h1o, WTao2, ao2_b, oe2, NTOK * 8, D_, AH_, 0, 0, 4); launch(b);
  }
  {
    B b; b.add(oe2, WToe, nullptr, ce_out, NTOK, 1024, 1024, 0, 0, 3); launch(b);
  }

  // scatter to d_out with token-type masking
  scatter_out<<<dim3(NTOK), dim3(256), 0, stream>>>(
      ct_out, ce_out, ttm, inv, out_text, out_ent);
}